// Round 3
// baseline (439.805 us; speedup 1.0000x reference)
//
#include <hip/hip_runtime.h>
#include <cstdint>
#include <cstddef>

typedef unsigned short u16;
typedef unsigned int   u32;
typedef __bf16  bf16x8 __attribute__((ext_vector_type(8)));
typedef float   f32x4  __attribute__((ext_vector_type(4)));

#define B_    2
#define N_    1024
#define K_    48
#define H_    128
#define CAT_  384
#define FF_   512
#define XAP   264   // bf16 row pitch for reduced X tile (256+8), 16B-aligned rows
#define YPAD  136   // bf16 row pitch for Y tiles (128+8)
#define MPAD  132   // fp32 row pitch for edge M tile
#define EPS_  1e-5f
#define INV_SCALE (1.0f/48.0f)

__device__ __forceinline__ float bf2f(u16 u){ u32 x=((u32)u)<<16; float f; __builtin_memcpy(&f,&x,4); return f; }
__device__ __forceinline__ u16 f2bf(float f){ u32 x; __builtin_memcpy(&x,&f,4); x=(x+0x7FFFu+((x>>16)&1u))>>16; return (u16)x; }
__device__ __forceinline__ u32 pk2(float lo, float hi){ return (u32)f2bf(lo) | ((u32)f2bf(hi)<<16); }

// Branch-free exact-GELU: erf via Abramowitz-Stegun 7.1.26 (|err|<=1.5e-7).
__device__ __forceinline__ float gelu_ex(float x){
    const float s = x * 0.7071067811865476f;
    const float a = fabsf(s);
    const float t = __builtin_amdgcn_rcpf(__builtin_fmaf(0.3275911f, a, 1.0f));
    float p = __builtin_fmaf(1.061405429f, t, -1.453152027f);
    p = __builtin_fmaf(p, t,  1.421413741f);
    p = __builtin_fmaf(p, t, -0.284496736f);
    p = __builtin_fmaf(p, t,  0.254829592f);
    p *= t;
    const float e = __expf(-s*s);
    const float erfa = __builtin_fmaf(-p, e, 1.0f);     // erf(|s|)
    const float erf  = __builtin_copysignf(erfa, s);
    return 0.5f*x*(1.0f+erf);
}
__device__ __forceinline__ f32x4 fzero(){ f32x4 v; v[0]=0.f; v[1]=0.f; v[2]=0.f; v[3]=0.f; return v; }

__device__ __forceinline__ float ldf(const void* p, size_t i, int bf){
    return bf ? bf2f(((const u16*)p)[i]) : ((const float*)p)[i];
}
// 8 consecutive elems -> bf16 LDS (dtype-aware; contract says fp32, probe is insurance)
__device__ __forceinline__ void cp8(u16* dst, const void* src, size_t eoff, int bf){
    if (bf) { *(uint4*)dst = *(const uint4*)((const u16*)src + eoff); }
    else {
        const float4* s = (const float4*)((const float*)src + eoff);
        float4 a = s[0], b = s[1];
        uint4 o; o.x = pk2(a.x,a.y); o.y = pk2(a.z,a.w); o.z = pk2(b.x,b.y); o.w = pk2(b.z,b.w);
        *(uint4*)dst = o;
    }
}

// ---------------- dtype probes ----------------
__device__ int probe_f_d(const void* p, int n_elems){
    const u32 w0 = ((const u32*)p)[0];
    if (w0 == 0x3F803F80u) return 1;
    if (w0 == 0x3F800000u) return 0;
    const u16* s = (const u16*)p;
    int m = n_elems < 128 ? n_elems : 128;
    for (int j = 0; j < m; j++) { float v = fabsf(bf2f(s[j])); if (v > 1e6f) return 0; }
    return 1;
}
__device__ int probe_i_d(const int* p){
    const u32* s = (const u32*)p;
    for (int j = 0; j < 128; j++) if (s[2*j+1] != 0u) return 0;
    return 1;
}
struct Ptrs27 { const void* p[27]; int n[27]; };
__global__ void __launch_bounds__(64)
probe_dtypes(Ptrs27 ptrs, int* __restrict__ flags)
{
    const int t = blockIdx.x;
    if (threadIdx.x != 0) return;
    flags[t] = (t == 2) ? probe_i_d((const int*)ptrs.p[t]) : probe_f_d(ptrs.p[t], ptrs.n[t]);
}

// weight [ri][co] -> bf16 [co][ri]
__global__ void __launch_bounds__(256)
repack_t(const void* __restrict__ src, u16* __restrict__ dst, int rows_in, int cols_out,
         const int* __restrict__ flags, int fidx)
{
    const int bf = flags[fidx];
    int i = blockIdx.x*256 + threadIdx.x;
    if (i < rows_in*cols_out) {
        int o = i % cols_out, r = i / cols_out;
        dst[o*rows_in + r] = bf ? ((const u16*)src)[i] : f2bf(((const float*)src)[i]);
    }
}

__global__ void __launch_bounds__(256)
prep_idx(const int* __restrict__ src, int* __restrict__ dst, int n, const int* __restrict__ flags)
{
    const int w64 = flags[2];
    int i = blockIdx.x*256 + threadIdx.x;
    if (i < n) dst[i] = w64 ? src[2*i] : src[i];
}

// ---- single-column-block GEMM pass (register-pressure-reduced) ----
// 48xKD (LDS, u16 pitch AP) @ W^T rows (pitch LD, col-offset KOFF), ONE 16-col
// block ct of this wave's 32-col range -> acc[3]. Per-pass live state: acc 12
// regs + a-frags 12 + b-frag 4 (vs 24+12+8 in the fused 2-col version).
// Per output column the k-accumulation order is identical -> bitwise-same.
template<int KD, int AP, int LD, int KOFF>
__device__ __forceinline__ void mfma3x1(const u16* As, const u16* __restrict__ wt, int tid, int ct, f32x4 acc[3])
{
    const int lane = tid & 63;
    const int l15  = lane & 15, q = lane >> 4;
    const int n0   = (tid >> 6) * 32 + ct*16;
    for (int k0 = 0; k0 < KD; k0 += 32) {
        const int ko = k0 + q*8;
        bf16x8 b0 = *(const bf16x8*)&wt[(size_t)(n0 + l15)*LD + KOFF + ko];
        bf16x8 a0 = *(const bf16x8*)&As[(l15     )*AP + ko];
        bf16x8 a1 = *(const bf16x8*)&As[(l15 + 16)*AP + ko];
        bf16x8 a2 = *(const bf16x8*)&As[(l15 + 32)*AP + ko];
        acc[0] = __builtin_amdgcn_mfma_f32_16x16x32_bf16(a0,b0,acc[0],0,0,0);
        acc[1] = __builtin_amdgcn_mfma_f32_16x16x32_bf16(a1,b0,acc[1],0,0,0);
        acc[2] = __builtin_amdgcn_mfma_f32_16x16x32_bf16(a2,b0,acc[2],0,0,0);
    }
}
// D[row=mt*16+(lane>>4)*4+r][col=(wave*32)+ct*16+(lane&15)]  (m89-verified C/D mapping)
template<bool BIAS>
__device__ __forceinline__ void epi_gelu1(const f32x4 acc[3], const void* __restrict__ bias, int bf,
                                          u16* Outs, int tid, int ct)
{
    const int lane = tid & 63, l15 = lane & 15, q = lane >> 4;
    const int col = (tid>>6)*32 + ct*16 + l15;
    float bv = 0.f;
    if constexpr (BIAS) bv = ldf(bias, col, bf);
    for (int mt = 0; mt < 3; mt++)
        for (int r = 0; r < 4; r++)
            Outs[(mt*16 + q*4 + r)*YPAD + col] = f2bf(gelu_ex(acc[mt][r] + bv));
}

// shared center GEMV: gv[c] = bias[c] + sum_k hc_bf16[k] * Wt[c*LD + k], k<128
__device__ __forceinline__ void center_gemv(const u16* hcs, const u16* __restrict__ wt, int LD,
                                            const void* __restrict__ bias, int bfb,
                                            float* gvs, int tid)
{
    if (tid < H_) {
        const uint4* wr = (const uint4*)(wt + (size_t)tid*LD);
        const uint4* hh = (const uint4*)hcs;
        float a = 0.f;
#pragma unroll
        for (int i = 0; i < H_/8; i++) {
            uint4 uw = wr[i], uh = hh[i];
            a = fmaf(bf2f((u16)uw.x),       bf2f((u16)uh.x),       a);
            a = fmaf(bf2f((u16)(uw.x>>16)), bf2f((u16)(uh.x>>16)), a);
            a = fmaf(bf2f((u16)uw.y),       bf2f((u16)uh.y),       a);
            a = fmaf(bf2f((u16)(uw.y>>16)), bf2f((u16)(uh.y>>16)), a);
            a = fmaf(bf2f((u16)uw.z),       bf2f((u16)uh.z),       a);
            a = fmaf(bf2f((u16)(uw.z>>16)), bf2f((u16)(uh.z>>16)), a);
            a = fmaf(bf2f((u16)uw.w),       bf2f((u16)uh.w),       a);
            a = fmaf(bf2f((u16)(uw.w>>16)), bf2f((u16)(uh.w>>16)), a);
        }
        gvs[tid] = a + ldf(bias, tid, bfb);
    }
}

// ================= node kernel: MFMA =================
// X tile is only [h_E | hv_nb] (256 cols): the hv_ex block is row-constant, handled
// as a shared 128x128 GEMV folded into the MFMA C-initializer.
// Register history: (256,4)->cap 128 total, spilled 194 MB (R1); (256,3)->cap 170,
// still spilled 106 MB since arch+acc naturally ~176+ (R2). This version halves the
// accumulator (ct-split passes) so the natural footprint fits under cap 170.
__global__ void __launch_bounds__(256, 3)
node_mfma(const void* __restrict__ hV, const void* __restrict__ hE, const int* __restrict__ idxn,
          const void* __restrict__ maskV, const void* __restrict__ maskAtt,
          const u16* __restrict__ w1t, const void* __restrict__ b1,
          const u16* __restrict__ w2t, const void* __restrict__ b2,
          const u16* __restrict__ w3t, const void* __restrict__ b3,
          const u16* __restrict__ wintt, const void* __restrict__ bin,
          const u16* __restrict__ woutt, const void* __restrict__ bout,
          const void* __restrict__ g1, const void* __restrict__ be1,
          const void* __restrict__ g2, const void* __restrict__ be2,
          const int* __restrict__ flags,
          float* __restrict__ outV, u16* __restrict__ wsVn)
{
    __shared__ __align__(16) u16 Xs[K_*XAP];     // 25,344 B; later aliased as Y2 tile
    __shared__ __align__(16) u16 Y1s[K_*YPAD];   // 13,056 B; later aliased as fp32 hid[512]
    __shared__ __align__(16) float scr[256];     // 1 KB union: {hcs,gvs} then {dhs,hvn1}
    __shared__ float matt[K_];
    __shared__ int   idxs[K_];
    __shared__ float stats[3];                   // mean, rstd, summask

    u16*   hcs  = (u16*)scr;                     // bytes    0..255  (center row, bf16)
    float* gvs  = scr + 64;                      // bytes  256..767  (center GEMV out)
    float* dhs  = scr;                           // bytes    0..511  (after GEMM3; hcs/gvs dead)
    float* hvn1 = scr + 128;                     // bytes 512..1023  (after LN1; gvs dead)

    const int bn  = blockIdx.x;
    const int b   = bn >> 10;
    const int tid = threadIdx.x;
    const int lane = tid & 63, w = tid >> 6;

    const int fHV = flags[0], fHE = flags[1], fMV = flags[3], fMA = flags[4];
    const int fb1 = flags[6], fb2 = flags[8], fb3 = flags[10];
    const int fbin = flags[18], fbout = flags[20];
    const int fg1 = flags[21], fbe1 = flags[22], fg2 = flags[23], fbe2 = flags[24];

    if (tid < K_) { idxs[tid] = idxn[bn*K_ + tid]; matt[tid] = ldf(maskAtt, (size_t)bn*K_ + tid, fMA); }
    __syncthreads();
    if (tid == 0) { float s=0.f; for (int k=0;k<K_;k++) s += matt[k]; stats[2] = s; }
    if (tid < 16) cp8(&hcs[tid*8], hV, (size_t)bn*H_ + (tid<<3), fHV);

    for (int u = tid; u < 768; u += 256) {
        const int row = u >> 4, c8 = (u & 15) << 3;
        cp8(&Xs[row*XAP + c8],      hE, ((size_t)bn*K_ + row)*H_ + c8, fHE);
        cp8(&Xs[row*XAP + H_ + c8], hV, ((size_t)b*N_ + idxs[row])*H_ + c8, fHV);
    }
    __syncthreads();

    // shared center GEMV (W1 rows 0..127), bias folded
    center_gemv(hcs, w1t, CAT_, b1, fb1, gvs, tid);
    __syncthreads();

    const int l15 = lane & 15, q = lane >> 4, n0 = w*32;

    // ---- GEMM1: two single-col-block passes (register-pressure split) ----
#pragma unroll 1
    for (int ct = 0; ct < 2; ct++) {
        f32x4 acc[3];
        const float g = gvs[n0 + ct*16 + l15];
        for (int mt=0; mt<3; mt++) for (int r=0; r<4; r++) acc[mt][r] = g;
        mfma3x1<256, XAP, CAT_, H_>(Xs, w1t, tid, ct, acc);   // W1 rows 128..383
        epi_gelu1<false>(acc, nullptr, 0, Y1s, tid, ct);
    }
    __syncthreads();                 // Y1 visible; everyone done reading Xs

    u16* Y2s = Xs;                   // alias X region as Y2 tile (pitch YPAD)
#pragma unroll 1
    for (int ct = 0; ct < 2; ct++) {
        f32x4 acc[3] = {fzero(), fzero(), fzero()};
        mfma3x1<H_, YPAD, H_, 0>(Y1s, w2t, tid, ct, acc);
        epi_gelu1<true>(acc, b2, fb2, Y2s, tid, ct);
    }
    __syncthreads();

#pragma unroll 1
    for (int ct = 0; ct < 2; ct++) {
        f32x4 acc[3] = {fzero(), fzero(), fzero()};
        mfma3x1<H_, YPAD, H_, 0>(Y2s, w3t, tid, ct, acc);
        // masked sum over K rows -> dh (this wave's 16-col block ct)
        float s0 = 0.f;
        for (int mt=0; mt<3; mt++)
            for (int r=0; r<4; r++)
                s0 += acc[mt][r]*matt[mt*16 + q*4 + r];
        s0 += __shfl_xor(s0,16); s0 += __shfl_xor(s0,32);
        if (q == 0) {
            const int col = n0 + ct*16 + l15;
            dhs[col] = (s0 + ldf(b3, col, fb3)*stats[2]) * INV_SCALE;
        }
    }
    __syncthreads();

    // ---- LN1 (h = hV + dh recomputed from global) ----
    if (w == 0) {
        float a = ldf(hV, (size_t)bn*H_ + lane,      fHV) + dhs[lane];
        float c = ldf(hV, (size_t)bn*H_ + lane + 64, fHV) + dhs[lane+64];
        float s = a + c, ss = a*a + c*c;
        for (int off=32; off>0; off>>=1) { s += __shfl_xor(s,off); ss += __shfl_xor(ss,off); }
        if (lane == 0) { float m = s*(1.f/H_); stats[0]=m; stats[1]=rsqrtf(ss*(1.f/H_)-m*m+EPS_); }
    }
    __syncthreads();
    if (tid < H_) {
        float h = ldf(hV, (size_t)bn*H_ + tid, fHV) + dhs[tid];
        hvn1[tid] = (h - stats[0])*stats[1]*ldf(g1,tid,fg1) + ldf(be1,tid,fbe1);
    }
    __syncthreads();

    // ---- FFN (bf16 weight rows, uint4 loads) ----
    float* hid = (float*)Y1s;        // alias Y1 region (dead) as fp32 hid[512]
    for (int j = tid; j < FF_; j += 256) {
        const uint4* wr = (const uint4*)(wintt + (size_t)j*H_);
        float a = 0.f;
        for (int i = 0; i < H_/8; i++) {
            uint4 u = wr[i];
            a += hvn1[8*i+0]*bf2f((u16)u.x) + hvn1[8*i+1]*bf2f((u16)(u.x>>16));
            a += hvn1[8*i+2]*bf2f((u16)u.y) + hvn1[8*i+3]*bf2f((u16)(u.y>>16));
            a += hvn1[8*i+4]*bf2f((u16)u.z) + hvn1[8*i+5]*bf2f((u16)(u.z>>16));
            a += hvn1[8*i+6]*bf2f((u16)u.w) + hvn1[8*i+7]*bf2f((u16)(u.w>>16));
        }
        hid[j] = gelu_ex(a + ldf(bin, j, fbin));
    }
    __syncthreads();
    if (tid < H_) {
        const uint4* wr = (const uint4*)(woutt + (size_t)tid*FF_);
        float a = 0.f;
        for (int i = 0; i < FF_/8; i++) {
            uint4 u = wr[i];
            a += hid[8*i+0]*bf2f((u16)u.x) + hid[8*i+1]*bf2f((u16)(u.x>>16));
            a += hid[8*i+2]*bf2f((u16)u.y) + hid[8*i+3]*bf2f((u16)(u.y>>16));
            a += hid[8*i+4]*bf2f((u16)u.z) + hid[8*i+5]*bf2f((u16)(u.z>>16));
            a += hid[8*i+6]*bf2f((u16)u.w) + hid[8*i+7]*bf2f((u16)(u.w>>16));
        }
        dhs[tid] = hvn1[tid] + a + ldf(bout, tid, fbout);   // dhs reused as h2 buffer
    }
    __syncthreads();
    // ---- LN2 + mask ----
    if (w == 0) {
        float a = dhs[lane], c = dhs[lane+64];
        float s = a + c, ss = a*a + c*c;
        for (int off=32; off>0; off>>=1) { s += __shfl_xor(s,off); ss += __shfl_xor(ss,off); }
        if (lane == 0) { float m = s*(1.f/H_); stats[0]=m; stats[1]=rsqrtf(ss*(1.f/H_)-m*m+EPS_); }
    }
    __syncthreads();
    if (tid < H_) {
        float v = (dhs[tid]-stats[0])*stats[1]*ldf(g2,tid,fg2) + ldf(be2,tid,fbe2);
        v *= ldf(maskV, bn, fMV);
        outV[(size_t)bn*H_ + tid] = v;          // fp32 output
        wsVn[(size_t)bn*H_ + tid] = f2bf(v);    // bf16 copy for edge staging
    }
}

// ================= edge kernel: MFMA =================
__global__ void __launch_bounds__(256, 3)
edge_mfma(const u16* __restrict__ wsVn, const void* __restrict__ hE, const int* __restrict__ idxn,
          const u16* __restrict__ w11t, const void* __restrict__ b11,
          const u16* __restrict__ w12t, const void* __restrict__ b12,
          const u16* __restrict__ w13t, const void* __restrict__ b13,
          const void* __restrict__ g3, const void* __restrict__ be3,
          const int* __restrict__ flags,
          float* __restrict__ outE)
{
    __shared__ __align__(16) u16 Xs[K_*XAP];    // 25,344 B; aliased as Y2, then fp32 M [48][132]
    __shared__ __align__(16) u16 Y1s[K_*YPAD];
    __shared__ __align__(16) float scr[192];    // hcs (256 B) + gvs (512 B)
    __shared__ int idxs[K_];

    u16*   hcs = (u16*)scr;
    float* gvs = scr + 64;

    const int bn  = blockIdx.x;
    const int b   = bn >> 10;
    const int tid = threadIdx.x;
    const int lane = tid & 63, w = tid >> 6;

    const int fHE = flags[1];
    const int fb11 = flags[12], fb12 = flags[14], fb13 = flags[16];
    const int fg3 = flags[25], fbe3 = flags[26];

    if (tid < K_) idxs[tid] = idxn[bn*K_ + tid];
    __syncthreads();

    const u16* hVb = wsVn + (size_t)b*N_*H_;
    if (tid < 16) *(uint4*)&hcs[tid*8] = *(const uint4*)&wsVn[(size_t)bn*H_ + (tid<<3)];
    for (int u = tid; u < 768; u += 256) {
        const int row = u >> 4, c8 = (u & 15) << 3;
        cp8(&Xs[row*XAP + c8], hE, ((size_t)bn*K_ + row)*H_ + c8, fHE);
        *(uint4*)&Xs[row*XAP + H_ + c8] = *(const uint4*)&hVb[(size_t)idxs[row]*H_ + c8];
    }
    __syncthreads();

    center_gemv(hcs, w11t, CAT_, b11, fb11, gvs, tid);
    __syncthreads();

    const int l15 = lane & 15, q = lane >> 4, n0 = w*32;

#pragma unroll 1
    for (int ct = 0; ct < 2; ct++) {
        f32x4 acc[3];
        const float g = gvs[n0 + ct*16 + l15];
        for (int mt=0; mt<3; mt++) for (int r=0; r<4; r++) acc[mt][r] = g;
        mfma3x1<256, XAP, CAT_, H_>(Xs, w11t, tid, ct, acc);
        epi_gelu1<false>(acc, nullptr, 0, Y1s, tid, ct);
    }
    __syncthreads();

    u16* Y2s = Xs;
#pragma unroll 1
    for (int ct = 0; ct < 2; ct++) {
        f32x4 acc[3] = {fzero(), fzero(), fzero()};
        mfma3x1<H_, YPAD, H_, 0>(Y1s, w12t, tid, ct, acc);
        epi_gelu1<true>(acc, b12, fb12, Y2s, tid, ct);
    }
    __syncthreads();

    // GEMM3 accumulates into registers; must finish BEFORE Xs is overwritten as Ms.
    f32x4 acc3[2][3];
#pragma unroll 1
    for (int ct = 0; ct < 2; ct++) {
        acc3[ct][0] = fzero(); acc3[ct][1] = fzero(); acc3[ct][2] = fzero();
        mfma3x1<H_, YPAD, H_, 0>(Y2s, w13t, tid, ct, acc3[ct]);
    }
    __syncthreads();                  // all layer-3 reads of Y2 (Xs) done
    float* Ms = (float*)Xs;           // fp32 M tile [48][MPAD] — exactly fits 48*264 u16
    for (int ct=0; ct<2; ct++) {
        const int col = n0 + ct*16 + l15;
        const float bv = ldf(b13, col, fb13);
        for (int mt=0; mt<3; mt++)
            for (int r=0; r<4; r++)
                Ms[(mt*16 + q*4 + r)*MPAD + col] = acc3[ct][mt][r] + bv;
    }
    __syncthreads();

    // h_En = LN(h_E + M), one wave per row, fp32 store
    for (int row = w; row < K_; row += 4) {
        const size_t e0 = ((size_t)bn*K_ + row)*H_;
        float v0 = ldf(hE, e0 + lane,      fHE) + Ms[row*MPAD + lane];
        float v1 = ldf(hE, e0 + lane + 64, fHE) + Ms[row*MPAD + lane + 64];
        float s = v0+v1, ss = v0*v0+v1*v1;
        for (int off=32; off>0; off>>=1) { s += __shfl_xor(s,off); ss += __shfl_xor(ss,off); }
        const float m = s*(1.f/H_);
        const float rstd = rsqrtf(ss*(1.f/H_) - m*m + EPS_);
        outE[e0 + lane]      = (v0-m)*rstd*ldf(g3,lane,fg3)    + ldf(be3,lane,fbe3);
        outE[e0 + lane + 64] = (v1-m)*rstd*ldf(g3,lane+64,fg3) + ldf(be3,lane+64,fbe3);
    }
}

extern "C" void kernel_launch(void* const* d_in, const int* in_sizes, int n_in,
                              void* d_out, int out_size, void* d_ws, size_t ws_size,
                              hipStream_t stream)
{
    const void* hV      = d_in[0];
    const void* hE      = d_in[1];
    const int*  Eidx    = (const int*)d_in[2];
    const void* maskV   = d_in[3];
    const void* maskAtt = d_in[4];
    const void* W1w  = d_in[5];  const void* W1b  = d_in[6];
    const void* W2w  = d_in[7];  const void* W2b  = d_in[8];
    const void* W3w  = d_in[9];  const void* W3b  = d_in[10];
    const void* W11w = d_in[11]; const void* W11b = d_in[12];
    const void* W12w = d_in[13]; const void* W12b = d_in[14];
    const void* W13w = d_in[15]; const void* W13b = d_in[16];
    const void* Winw = d_in[17]; const void* Winb = d_in[18];
    const void* Woutw= d_in[19]; const void* Woutb= d_in[20];
    const void* ln1g = d_in[21]; const void* ln1b = d_in[22];
    const void* ln2g = d_in[23]; const void* ln2b = d_in[24];
    const void* ln3g = d_in[25]; const void* ln3b = d_in[26];

    // ws layout (u16 units)
    u16* ws    = (u16*)d_ws;
    u16* w1t   = ws;                        // 128*384
    u16* w2t   = w1t   + 128*384;           // 128*128
    u16* w3t   = w2t   + 128*128;
    u16* w11t  = w3t   + 128*128;           // 128*384
    u16* w12t  = w11t  + 128*384;
    u16* w13t  = w12t  + 128*128;
    u16* wintt = w13t  + 128*128;           // 512*128
    u16* woutt = wintt + 512*128;           // 128*512
    int* idxn  = (int*)(woutt + 128*512);   // 98304 int32
    u16* wsVn  = (u16*)(idxn + B_*N_*K_);   // 262144 bf16
    int* flags = (int*)(wsVn + B_*N_*H_);   // 27 ints

    Ptrs27 P;
    for (int i = 0; i < 27; i++) { P.p[i] = d_in[i]; P.n[i] = in_sizes[i]; }
    hipLaunchKernelGGL(probe_dtypes, dim3(27), dim3(64), 0, stream, P, flags);

    auto T = [&](const void* src, u16* dst, int ri, int co, int fidx) {
        hipLaunchKernelGGL(repack_t, dim3((ri*co+255)/256), dim3(256), 0, stream, src, dst, ri, co, flags, fidx);
    };
    T(W1w,  w1t,  384, 128, 5);
    T(W2w,  w2t,  128, 128, 7);
    T(W3w,  w3t,  128, 128, 9);
    T(W11w, w11t, 384, 128, 11);
    T(W12w, w12t, 128, 128, 13);
    T(W13w, w13t, 128, 128, 15);
    T(Winw, wintt, 128, 512, 17);
    T(Woutw,woutt, 512, 128, 19);
    hipLaunchKernelGGL(prep_idx, dim3((B_*N_*K_+255)/256), dim3(256), 0, stream, Eidx, idxn, B_*N_*K_, flags);

    float* outV = (float*)d_out;
    float* outE = outV + (size_t)B_*N_*H_;

    hipLaunchKernelGGL(node_mfma, dim3(B_*N_), dim3(256), 0, stream,
                       hV, hE, idxn, maskV, maskAtt,
                       w1t, W1b, w2t, W2b, w3t, W3b,
                       wintt, Winb, woutt, Woutb,
                       ln1g, ln1b, ln2g, ln2b,
                       flags, outV, wsVn);
    hipLaunchKernelGGL(edge_mfma, dim3(B_*N_), dim3(256), 0, stream,
                       wsVn, hE, idxn,
                       w11t, W11b, w12t, W12b, w13t, W13b,
                       ln3g, ln3b, flags, outE);
}

// Round 4
// 398.713 us; speedup vs baseline: 1.1031x; 1.1031x over previous
//
#include <hip/hip_runtime.h>
#include <cstdint>
#include <cstddef>

typedef unsigned short u16;
typedef unsigned int   u32;
typedef __bf16  bf16x8 __attribute__((ext_vector_type(8)));
typedef float   f32x4  __attribute__((ext_vector_type(4)));

#define B_    2
#define N_    1024
#define K_    48
#define H_    128
#define CAT_  384
#define FF_   512
#define XAP   264   // bf16 row pitch for reduced X tile (256+8), 16B-aligned rows
#define YPAD  136   // bf16 row pitch for Y tiles (128+8)
#define MPAD  132   // fp32 row pitch for edge M tile
#define EPS_  1e-5f
#define INV_SCALE (1.0f/48.0f)

__device__ __forceinline__ float bf2f(u16 u){ u32 x=((u32)u)<<16; float f; __builtin_memcpy(&f,&x,4); return f; }
__device__ __forceinline__ u16 f2bf(float f){ u32 x; __builtin_memcpy(&x,&f,4); x=(x+0x7FFFu+((x>>16)&1u))>>16; return (u16)x; }
__device__ __forceinline__ u32 pk2(float lo, float hi){ return (u32)f2bf(lo) | ((u32)f2bf(hi)<<16); }

// Branch-free exact-GELU: erf via Abramowitz-Stegun 7.1.26 (|err|<=1.5e-7).
__device__ __forceinline__ float gelu_ex(float x){
    const float s = x * 0.7071067811865476f;
    const float a = fabsf(s);
    const float t = __builtin_amdgcn_rcpf(__builtin_fmaf(0.3275911f, a, 1.0f));
    float p = __builtin_fmaf(1.061405429f, t, -1.453152027f);
    p = __builtin_fmaf(p, t,  1.421413741f);
    p = __builtin_fmaf(p, t, -0.284496736f);
    p = __builtin_fmaf(p, t,  0.254829592f);
    p *= t;
    const float e = __expf(-s*s);
    const float erfa = __builtin_fmaf(-p, e, 1.0f);     // erf(|s|)
    const float erf  = __builtin_copysignf(erfa, s);
    return 0.5f*x*(1.0f+erf);
}
__device__ __forceinline__ f32x4 fzero(){ f32x4 v; v[0]=0.f; v[1]=0.f; v[2]=0.f; v[3]=0.f; return v; }

__device__ __forceinline__ float ldf(const void* p, size_t i, int bf){
    return bf ? bf2f(((const u16*)p)[i]) : ((const float*)p)[i];
}
// 8 consecutive elems -> bf16 LDS (dtype-aware; contract says fp32, probe is insurance)
__device__ __forceinline__ void cp8(u16* dst, const void* src, size_t eoff, int bf){
    if (bf) { *(uint4*)dst = *(const uint4*)((const u16*)src + eoff); }
    else {
        const float4* s = (const float4*)((const float*)src + eoff);
        float4 a = s[0], b = s[1];
        uint4 o; o.x = pk2(a.x,a.y); o.y = pk2(a.z,a.w); o.z = pk2(b.x,b.y); o.w = pk2(b.z,b.w);
        *(uint4*)dst = o;
    }
}
// 8-wide bf16 dot-accumulate from two uint4s
__device__ __forceinline__ float dot8(uint4 uw, uint4 uh, float a){
    a = fmaf(bf2f((u16)uw.x),       bf2f((u16)uh.x),       a);
    a = fmaf(bf2f((u16)(uw.x>>16)), bf2f((u16)(uh.x>>16)), a);
    a = fmaf(bf2f((u16)uw.y),       bf2f((u16)uh.y),       a);
    a = fmaf(bf2f((u16)(uw.y>>16)), bf2f((u16)(uh.y>>16)), a);
    a = fmaf(bf2f((u16)uw.z),       bf2f((u16)uh.z),       a);
    a = fmaf(bf2f((u16)(uw.z>>16)), bf2f((u16)(uh.z>>16)), a);
    a = fmaf(bf2f((u16)uw.w),       bf2f((u16)uh.w),       a);
    a = fmaf(bf2f((u16)(uw.w>>16)), bf2f((u16)(uh.w>>16)), a);
    return a;
}

// ---------------- dtype probes ----------------
__device__ int probe_f_d(const void* p, int n_elems){
    const u32 w0 = ((const u32*)p)[0];
    if (w0 == 0x3F803F80u) return 1;
    if (w0 == 0x3F800000u) return 0;
    const u16* s = (const u16*)p;
    int m = n_elems < 128 ? n_elems : 128;
    for (int j = 0; j < m; j++) { float v = fabsf(bf2f(s[j])); if (v > 1e6f) return 0; }
    return 1;
}
__device__ int probe_i_d(const int* p){
    const u32* s = (const u32*)p;
    for (int j = 0; j < 128; j++) if (s[2*j+1] != 0u) return 0;
    return 1;
}
struct Ptrs27 { const void* p[27]; int n[27]; };
__global__ void __launch_bounds__(64)
probe_dtypes(Ptrs27 ptrs, int* __restrict__ flags)
{
    const int t = blockIdx.x;
    if (threadIdx.x != 0) return;
    flags[t] = (t == 2) ? probe_i_d((const int*)ptrs.p[t]) : probe_f_d(ptrs.p[t], ptrs.n[t]);
}

// weight [ri][co] -> bf16 [co][ri]
__global__ void __launch_bounds__(256)
repack_t(const void* __restrict__ src, u16* __restrict__ dst, int rows_in, int cols_out,
         const int* __restrict__ flags, int fidx)
{
    const int bf = flags[fidx];
    int i = blockIdx.x*256 + threadIdx.x;
    if (i < rows_in*cols_out) {
        int o = i % cols_out, r = i / cols_out;
        dst[o*rows_in + r] = bf ? ((const u16*)src)[i] : f2bf(((const float*)src)[i]);
    }
}

__global__ void __launch_bounds__(256)
prep_idx(const int* __restrict__ src, int* __restrict__ dst, int n, const int* __restrict__ flags)
{
    const int w64 = flags[2];
    int i = blockIdx.x*256 + threadIdx.x;
    if (i < n) dst[i] = w64 ? src[2*i] : src[i];
}

// ---- single-column-block GEMM pass (register-pressure-reduced) ----
// 48xKD (LDS, u16 pitch AP) @ W^T rows (pitch LD, col-offset KOFF), ONE 16-col
// block ct of this wave's 32-col range -> acc[3].
template<int KD, int AP, int LD, int KOFF>
__device__ __forceinline__ void mfma3x1(const u16* As, const u16* __restrict__ wt, int tid, int ct, f32x4 acc[3])
{
    const int lane = tid & 63;
    const int l15  = lane & 15, q = lane >> 4;
    const int n0   = (tid >> 6) * 32 + ct*16;
    for (int k0 = 0; k0 < KD; k0 += 32) {
        const int ko = k0 + q*8;
        bf16x8 b0 = *(const bf16x8*)&wt[(size_t)(n0 + l15)*LD + KOFF + ko];
        bf16x8 a0 = *(const bf16x8*)&As[(l15     )*AP + ko];
        bf16x8 a1 = *(const bf16x8*)&As[(l15 + 16)*AP + ko];
        bf16x8 a2 = *(const bf16x8*)&As[(l15 + 32)*AP + ko];
        acc[0] = __builtin_amdgcn_mfma_f32_16x16x32_bf16(a0,b0,acc[0],0,0,0);
        acc[1] = __builtin_amdgcn_mfma_f32_16x16x32_bf16(a1,b0,acc[1],0,0,0);
        acc[2] = __builtin_amdgcn_mfma_f32_16x16x32_bf16(a2,b0,acc[2],0,0,0);
    }
}
// D[row=mt*16+(lane>>4)*4+r][col=(wave*32)+ct*16+(lane&15)]  (m89-verified C/D mapping)
template<bool BIAS>
__device__ __forceinline__ void epi_gelu1(const f32x4 acc[3], const void* __restrict__ bias, int bf,
                                          u16* Outs, int tid, int ct)
{
    const int lane = tid & 63, l15 = lane & 15, q = lane >> 4;
    const int col = (tid>>6)*32 + ct*16 + l15;
    float bv = 0.f;
    if constexpr (BIAS) bv = ldf(bias, col, bf);
    for (int mt = 0; mt < 3; mt++)
        for (int r = 0; r < 4; r++)
            Outs[(mt*16 + q*4 + r)*YPAD + col] = f2bf(gelu_ex(acc[mt][r] + bv));
}

// shared center GEMV: gv[c] = bias[c] + sum_k hc_bf16[k] * Wt[c*LD + k], k<128
// unroll BOUNDED at 4: R1-R3 post-mortems showed the full 16-iter unroll here
// hoisted ~32 uint4 loads -> ~128 live VGPRs -> 50-92 regs of loop-resident
// scratch spill (106-194 MB HBM writes/dispatch). 4 iters x 2 uint4 = 32 regs.
__device__ __forceinline__ void center_gemv(const u16* hcs, const u16* __restrict__ wt, int LD,
                                            const void* __restrict__ bias, int bfb,
                                            float* gvs, int tid)
{
    if (tid < H_) {
        const uint4* wr = (const uint4*)(wt + (size_t)tid*LD);
        const uint4* hh = (const uint4*)hcs;
        float a = 0.f;
#pragma unroll 4
        for (int i = 0; i < H_/8; i++) a = dot8(wr[i], hh[i], a);
        gvs[tid] = a + ldf(bias, tid, bfb);
    }
}

// ================= node kernel: MFMA =================
// X tile is only [h_E | hv_nb] (256 cols): the hv_ex block is row-constant, handled
// as a shared 128x128 GEMV folded into the MFMA C-initializer.
__global__ void __launch_bounds__(256, 3)
node_mfma(const void* __restrict__ hV, const void* __restrict__ hE, const int* __restrict__ idxn,
          const void* __restrict__ maskV, const void* __restrict__ maskAtt,
          const u16* __restrict__ w1t, const void* __restrict__ b1,
          const u16* __restrict__ w2t, const void* __restrict__ b2,
          const u16* __restrict__ w3t, const void* __restrict__ b3,
          const u16* __restrict__ wintt, const void* __restrict__ bin,
          const u16* __restrict__ woutt, const void* __restrict__ bout,
          const void* __restrict__ g1, const void* __restrict__ be1,
          const void* __restrict__ g2, const void* __restrict__ be2,
          const int* __restrict__ flags,
          float* __restrict__ outV, u16* __restrict__ wsVn)
{
    __shared__ __align__(16) u16 Xs[K_*XAP];     // 25,344 B; later aliased as Y2 tile
    __shared__ __align__(16) u16 Y1s[K_*YPAD];   // 13,056 B; later aliased as fp32 hid[512]
    __shared__ __align__(16) float scr[256];     // 1 KB union: {hcs,gvs} then {dhs,hvn1}
    __shared__ float matt[K_];
    __shared__ int   idxs[K_];
    __shared__ float stats[3];                   // mean, rstd, summask

    u16*   hcs  = (u16*)scr;                     // bytes    0..255  (center row, bf16)
    float* gvs  = scr + 64;                      // bytes  256..767  (center GEMV out)
    float* dhs  = scr;                           // bytes    0..511  (after GEMM3; hcs/gvs dead)
    float* hvn1 = scr + 128;                     // bytes 512..1023  (after LN1; gvs dead)

    const int bn  = blockIdx.x;
    const int b   = bn >> 10;
    const int tid = threadIdx.x;
    const int lane = tid & 63, w = tid >> 6;

    const int fHV = flags[0], fHE = flags[1], fMV = flags[3], fMA = flags[4];
    const int fb1 = flags[6], fb2 = flags[8], fb3 = flags[10];
    const int fbin = flags[18], fbout = flags[20];
    const int fg1 = flags[21], fbe1 = flags[22], fg2 = flags[23], fbe2 = flags[24];

    if (tid < K_) { idxs[tid] = idxn[bn*K_ + tid]; matt[tid] = ldf(maskAtt, (size_t)bn*K_ + tid, fMA); }
    __syncthreads();
    if (tid == 0) { float s=0.f; for (int k=0;k<K_;k++) s += matt[k]; stats[2] = s; }
    if (tid < 16) cp8(&hcs[tid*8], hV, (size_t)bn*H_ + (tid<<3), fHV);

    for (int u = tid; u < 768; u += 256) {
        const int row = u >> 4, c8 = (u & 15) << 3;
        cp8(&Xs[row*XAP + c8],      hE, ((size_t)bn*K_ + row)*H_ + c8, fHE);
        cp8(&Xs[row*XAP + H_ + c8], hV, ((size_t)b*N_ + idxs[row])*H_ + c8, fHV);
    }
    __syncthreads();

    // shared center GEMV (W1 rows 0..127), bias folded
    center_gemv(hcs, w1t, CAT_, b1, fb1, gvs, tid);
    __syncthreads();

    const int l15 = lane & 15, q = lane >> 4, n0 = w*32;

    // ---- GEMM1: two single-col-block passes (register-pressure split) ----
#pragma unroll 1
    for (int ct = 0; ct < 2; ct++) {
        f32x4 acc[3];
        const float g = gvs[n0 + ct*16 + l15];
        for (int mt=0; mt<3; mt++) for (int r=0; r<4; r++) acc[mt][r] = g;
        mfma3x1<256, XAP, CAT_, H_>(Xs, w1t, tid, ct, acc);   // W1 rows 128..383
        epi_gelu1<false>(acc, nullptr, 0, Y1s, tid, ct);
    }
    __syncthreads();                 // Y1 visible; everyone done reading Xs

    u16* Y2s = Xs;                   // alias X region as Y2 tile (pitch YPAD)
#pragma unroll 1
    for (int ct = 0; ct < 2; ct++) {
        f32x4 acc[3] = {fzero(), fzero(), fzero()};
        mfma3x1<H_, YPAD, H_, 0>(Y1s, w2t, tid, ct, acc);
        epi_gelu1<true>(acc, b2, fb2, Y2s, tid, ct);
    }
    __syncthreads();

#pragma unroll 1
    for (int ct = 0; ct < 2; ct++) {
        f32x4 acc[3] = {fzero(), fzero(), fzero()};
        mfma3x1<H_, YPAD, H_, 0>(Y2s, w3t, tid, ct, acc);
        // masked sum over K rows -> dh (this wave's 16-col block ct)
        float s0 = 0.f;
        for (int mt=0; mt<3; mt++)
            for (int r=0; r<4; r++)
                s0 += acc[mt][r]*matt[mt*16 + q*4 + r];
        s0 += __shfl_xor(s0,16); s0 += __shfl_xor(s0,32);
        if (q == 0) {
            const int col = n0 + ct*16 + l15;
            dhs[col] = (s0 + ldf(b3, col, fb3)*stats[2]) * INV_SCALE;
        }
    }
    __syncthreads();

    // ---- LN1 (h = hV + dh recomputed from global) ----
    if (w == 0) {
        float a = ldf(hV, (size_t)bn*H_ + lane,      fHV) + dhs[lane];
        float c = ldf(hV, (size_t)bn*H_ + lane + 64, fHV) + dhs[lane+64];
        float s = a + c, ss = a*a + c*c;
        for (int off=32; off>0; off>>=1) { s += __shfl_xor(s,off); ss += __shfl_xor(ss,off); }
        if (lane == 0) { float m = s*(1.f/H_); stats[0]=m; stats[1]=rsqrtf(ss*(1.f/H_)-m*m+EPS_); }
    }
    __syncthreads();
    if (tid < H_) {
        float h = ldf(hV, (size_t)bn*H_ + tid, fHV) + dhs[tid];
        hvn1[tid] = (h - stats[0])*stats[1]*ldf(g1,tid,fg1) + ldf(be1,tid,fbe1);
    }
    __syncthreads();

    // ---- FFN (bf16 weight rows, uint4 loads; unroll bounded for reg pressure) ----
    float* hid = (float*)Y1s;        // alias Y1 region (dead) as fp32 hid[512]
    const uint4* hv4 = (const uint4*)hvn1;   // fp32 pairs, read via LDS as floats below
    for (int j = tid; j < FF_; j += 256) {
        const uint4* wr = (const uint4*)(wintt + (size_t)j*H_);
        float a = 0.f;
#pragma unroll 4
        for (int i = 0; i < H_/8; i++) {
            uint4 u = wr[i];
            a += hvn1[8*i+0]*bf2f((u16)u.x) + hvn1[8*i+1]*bf2f((u16)(u.x>>16));
            a += hvn1[8*i+2]*bf2f((u16)u.y) + hvn1[8*i+3]*bf2f((u16)(u.y>>16));
            a += hvn1[8*i+4]*bf2f((u16)u.z) + hvn1[8*i+5]*bf2f((u16)(u.z>>16));
            a += hvn1[8*i+6]*bf2f((u16)u.w) + hvn1[8*i+7]*bf2f((u16)(u.w>>16));
        }
        hid[j] = gelu_ex(a + ldf(bin, j, fbin));
    }
    __syncthreads();
    if (tid < H_) {
        const uint4* wr = (const uint4*)(woutt + (size_t)tid*FF_);
        float a = 0.f;
#pragma unroll 4
        for (int i = 0; i < FF_/8; i++) {
            uint4 u = wr[i];
            a += hid[8*i+0]*bf2f((u16)u.x) + hid[8*i+1]*bf2f((u16)(u.x>>16));
            a += hid[8*i+2]*bf2f((u16)u.y) + hid[8*i+3]*bf2f((u16)(u.y>>16));
            a += hid[8*i+4]*bf2f((u16)u.z) + hid[8*i+5]*bf2f((u16)(u.z>>16));
            a += hid[8*i+6]*bf2f((u16)u.w) + hid[8*i+7]*bf2f((u16)(u.w>>16));
        }
        dhs[tid] = hvn1[tid] + a + ldf(bout, tid, fbout);   // dhs reused as h2 buffer
    }
    __syncthreads();
    // ---- LN2 + mask ----
    if (w == 0) {
        float a = dhs[lane], c = dhs[lane+64];
        float s = a + c, ss = a*a + c*c;
        for (int off=32; off>0; off>>=1) { s += __shfl_xor(s,off); ss += __shfl_xor(ss,off); }
        if (lane == 0) { float m = s*(1.f/H_); stats[0]=m; stats[1]=rsqrtf(ss*(1.f/H_)-m*m+EPS_); }
    }
    __syncthreads();
    if (tid < H_) {
        float v = (dhs[tid]-stats[0])*stats[1]*ldf(g2,tid,fg2) + ldf(be2,tid,fbe2);
        v *= ldf(maskV, bn, fMV);
        outV[(size_t)bn*H_ + tid] = v;          // fp32 output
        wsVn[(size_t)bn*H_ + tid] = f2bf(v);    // bf16 copy for edge staging
    }
}

// ================= edge kernel: MFMA =================
__global__ void __launch_bounds__(256, 3)
edge_mfma(const u16* __restrict__ wsVn, const void* __restrict__ hE, const int* __restrict__ idxn,
          const u16* __restrict__ w11t, const void* __restrict__ b11,
          const u16* __restrict__ w12t, const void* __restrict__ b12,
          const u16* __restrict__ w13t, const void* __restrict__ b13,
          const void* __restrict__ g3, const void* __restrict__ be3,
          const int* __restrict__ flags,
          float* __restrict__ outE)
{
    __shared__ __align__(16) u16 Xs[K_*XAP];    // 25,344 B; aliased as Y2, then fp32 M [48][132]
    __shared__ __align__(16) u16 Y1s[K_*YPAD];
    __shared__ __align__(16) float scr[192];    // hcs (256 B) + gvs (512 B)
    __shared__ int idxs[K_];

    u16*   hcs = (u16*)scr;
    float* gvs = scr + 64;

    const int bn  = blockIdx.x;
    const int b   = bn >> 10;
    const int tid = threadIdx.x;
    const int lane = tid & 63, w = tid >> 6;

    const int fHE = flags[1];
    const int fb11 = flags[12], fb12 = flags[14], fb13 = flags[16];
    const int fg3 = flags[25], fbe3 = flags[26];

    if (tid < K_) idxs[tid] = idxn[bn*K_ + tid];
    __syncthreads();

    const u16* hVb = wsVn + (size_t)b*N_*H_;
    if (tid < 16) *(uint4*)&hcs[tid*8] = *(const uint4*)&wsVn[(size_t)bn*H_ + (tid<<3)];
    for (int u = tid; u < 768; u += 256) {
        const int row = u >> 4, c8 = (u & 15) << 3;
        cp8(&Xs[row*XAP + c8], hE, ((size_t)bn*K_ + row)*H_ + c8, fHE);
        *(uint4*)&Xs[row*XAP + H_ + c8] = *(const uint4*)&hVb[(size_t)idxs[row]*H_ + c8];
    }
    __syncthreads();

    center_gemv(hcs, w11t, CAT_, b11, fb11, gvs, tid);
    __syncthreads();

    const int l15 = lane & 15, q = lane >> 4, n0 = w*32;

#pragma unroll 1
    for (int ct = 0; ct < 2; ct++) {
        f32x4 acc[3];
        const float g = gvs[n0 + ct*16 + l15];
        for (int mt=0; mt<3; mt++) for (int r=0; r<4; r++) acc[mt][r] = g;
        mfma3x1<256, XAP, CAT_, H_>(Xs, w11t, tid, ct, acc);
        epi_gelu1<false>(acc, nullptr, 0, Y1s, tid, ct);
    }
    __syncthreads();

    u16* Y2s = Xs;
#pragma unroll 1
    for (int ct = 0; ct < 2; ct++) {
        f32x4 acc[3] = {fzero(), fzero(), fzero()};
        mfma3x1<H_, YPAD, H_, 0>(Y1s, w12t, tid, ct, acc);
        epi_gelu1<true>(acc, b12, fb12, Y2s, tid, ct);
    }
    __syncthreads();

    // GEMM3 accumulates into registers; must finish BEFORE Xs is overwritten as Ms.
    f32x4 acc3[2][3];
#pragma unroll 1
    for (int ct = 0; ct < 2; ct++) {
        acc3[ct][0] = fzero(); acc3[ct][1] = fzero(); acc3[ct][2] = fzero();
        mfma3x1<H_, YPAD, H_, 0>(Y2s, w13t, tid, ct, acc3[ct]);
    }
    __syncthreads();                  // all layer-3 reads of Y2 (Xs) done
    float* Ms = (float*)Xs;           // fp32 M tile [48][MPAD] — exactly fits 48*264 u16
    for (int ct=0; ct<2; ct++) {
        const int col = n0 + ct*16 + l15;
        const float bv = ldf(b13, col, fb13);
        for (int mt=0; mt<3; mt++)
            for (int r=0; r<4; r++)
                Ms[(mt*16 + q*4 + r)*MPAD + col] = acc3[ct][mt][r] + bv;
    }
    __syncthreads();

    // h_En = LN(h_E + M), one wave per row, fp32 store
    for (int row = w; row < K_; row += 4) {
        const size_t e0 = ((size_t)bn*K_ + row)*H_;
        float v0 = ldf(hE, e0 + lane,      fHE) + Ms[row*MPAD + lane];
        float v1 = ldf(hE, e0 + lane + 64, fHE) + Ms[row*MPAD + lane + 64];
        float s = v0+v1, ss = v0*v0+v1*v1;
        for (int off=32; off>0; off>>=1) { s += __shfl_xor(s,off); ss += __shfl_xor(ss,off); }
        const float m = s*(1.f/H_);
        const float rstd = rsqrtf(ss*(1.f/H_) - m*m + EPS_);
        outE[e0 + lane]      = (v0-m)*rstd*ldf(g3,lane,fg3)    + ldf(be3,lane,fbe3);
        outE[e0 + lane + 64] = (v1-m)*rstd*ldf(g3,lane+64,fg3) + ldf(be3,lane+64,fbe3);
    }
}

extern "C" void kernel_launch(void* const* d_in, const int* in_sizes, int n_in,
                              void* d_out, int out_size, void* d_ws, size_t ws_size,
                              hipStream_t stream)
{
    const void* hV      = d_in[0];
    const void* hE      = d_in[1];
    const int*  Eidx    = (const int*)d_in[2];
    const void* maskV   = d_in[3];
    const void* maskAtt = d_in[4];
    const void* W1w  = d_in[5];  const void* W1b  = d_in[6];
    const void* W2w  = d_in[7];  const void* W2b  = d_in[8];
    const void* W3w  = d_in[9];  const void* W3b  = d_in[10];
    const void* W11w = d_in[11]; const void* W11b = d_in[12];
    const void* W12w = d_in[13]; const void* W12b = d_in[14];
    const void* W13w = d_in[15]; const void* W13b = d_in[16];
    const void* Winw = d_in[17]; const void* Winb = d_in[18];
    const void* Woutw= d_in[19]; const void* Woutb= d_in[20];
    const void* ln1g = d_in[21]; const void* ln1b = d_in[22];
    const void* ln2g = d_in[23]; const void* ln2b = d_in[24];
    const void* ln3g = d_in[25]; const void* ln3b = d_in[26];

    // ws layout (u16 units)
    u16* ws    = (u16*)d_ws;
    u16* w1t   = ws;                        // 128*384
    u16* w2t   = w1t   + 128*384;           // 128*128
    u16* w3t   = w2t   + 128*128;
    u16* w11t  = w3t   + 128*128;           // 128*384
    u16* w12t  = w11t  + 128*384;
    u16* w13t  = w12t  + 128*128;
    u16* wintt = w13t  + 128*128;           // 512*128
    u16* woutt = wintt + 512*128;           // 128*512
    int* idxn  = (int*)(woutt + 128*512);   // 98304 int32
    u16* wsVn  = (u16*)(idxn + B_*N_*K_);   // 262144 bf16
    int* flags = (int*)(wsVn + B_*N_*H_);   // 27 ints

    Ptrs27 P;
    for (int i = 0; i < 27; i++) { P.p[i] = d_in[i]; P.n[i] = in_sizes[i]; }
    hipLaunchKernelGGL(probe_dtypes, dim3(27), dim3(64), 0, stream, P, flags);

    auto T = [&](const void* src, u16* dst, int ri, int co, int fidx) {
        hipLaunchKernelGGL(repack_t, dim3((ri*co+255)/256), dim3(256), 0, stream, src, dst, ri, co, flags, fidx);
    };
    T(W1w,  w1t,  384, 128, 5);
    T(W2w,  w2t,  128, 128, 7);
    T(W3w,  w3t,  128, 128, 9);
    T(W11w, w11t, 384, 128, 11);
    T(W12w, w12t, 128, 128, 13);
    T(W13w, w13t, 128, 128, 15);
    T(Winw, wintt, 128, 512, 17);
    T(Woutw,woutt, 512, 128, 19);
    hipLaunchKernelGGL(prep_idx, dim3((B_*N_*K_+255)/256), dim3(256), 0, stream, Eidx, idxn, B_*N_*K_, flags);

    float* outV = (float*)d_out;
    float* outE = outV + (size_t)B_*N_*H_;

    hipLaunchKernelGGL(node_mfma, dim3(B_*N_), dim3(256), 0, stream,
                       hV, hE, idxn, maskV, maskAtt,
                       w1t, W1b, w2t, W2b, w3t, W3b,
                       wintt, Winb, woutt, Woutb,
                       ln1g, ln1b, ln2g, ln2b,
                       flags, outV, wsVn);
    hipLaunchKernelGGL(edge_mfma, dim3(B_*N_), dim3(256), 0, stream,
                       wsVn, hE, idxn,
                       w11t, W11b, w12t, W12b, w13t, W13b,
                       ln3g, ln3b, flags, outE);
}

// Round 5
// 376.985 us; speedup vs baseline: 1.1666x; 1.0576x over previous
//
#include <hip/hip_runtime.h>
#include <cstdint>
#include <cstddef>

typedef unsigned short u16;
typedef unsigned int   u32;
typedef __bf16  bf16x8 __attribute__((ext_vector_type(8)));
typedef float   f32x4  __attribute__((ext_vector_type(4)));

#define B_    2
#define N_    1024
#define K_    48
#define H_    128
#define CAT_  384
#define FF_   512
#define XAP   264   // bf16 row pitch for reduced X tile (256+8), 16B-aligned rows
#define YPAD  136   // bf16 row pitch for Y tiles (128+8)
#define MPAD  132   // fp32 row pitch for edge M tile
#define EPS_  1e-5f
#define INV_SCALE (1.0f/48.0f)

__device__ __forceinline__ float bf2f(u16 u){ u32 x=((u32)u)<<16; float f; __builtin_memcpy(&f,&x,4); return f; }
__device__ __forceinline__ u16 f2bf(float f){ u32 x; __builtin_memcpy(&x,&f,4); x=(x+0x7FFFu+((x>>16)&1u))>>16; return (u16)x; }
__device__ __forceinline__ u32 pk2(float lo, float hi){ return (u32)f2bf(lo) | ((u32)f2bf(hi)<<16); }

// Branch-free exact-GELU: erf via Abramowitz-Stegun 7.1.26 (|err|<=1.5e-7).
__device__ __forceinline__ float gelu_ex(float x){
    const float s = x * 0.7071067811865476f;
    const float a = fabsf(s);
    const float t = __builtin_amdgcn_rcpf(__builtin_fmaf(0.3275911f, a, 1.0f));
    float p = __builtin_fmaf(1.061405429f, t, -1.453152027f);
    p = __builtin_fmaf(p, t,  1.421413741f);
    p = __builtin_fmaf(p, t, -0.284496736f);
    p = __builtin_fmaf(p, t,  0.254829592f);
    p *= t;
    const float e = __expf(-s*s);
    const float erfa = __builtin_fmaf(-p, e, 1.0f);     // erf(|s|)
    const float erf  = __builtin_copysignf(erfa, s);
    return 0.5f*x*(1.0f+erf);
}
__device__ __forceinline__ f32x4 fzero(){ f32x4 v; v[0]=0.f; v[1]=0.f; v[2]=0.f; v[3]=0.f; return v; }

__device__ __forceinline__ float ldf(const void* p, size_t i, int bf){
    return bf ? bf2f(((const u16*)p)[i]) : ((const float*)p)[i];
}
// 8 consecutive elems -> bf16 LDS (dtype-aware; contract says fp32, probe is insurance)
__device__ __forceinline__ void cp8(u16* dst, const void* src, size_t eoff, int bf){
    if (bf) { *(uint4*)dst = *(const uint4*)((const u16*)src + eoff); }
    else {
        const float4* s = (const float4*)((const float*)src + eoff);
        float4 a = s[0], b = s[1];
        uint4 o; o.x = pk2(a.x,a.y); o.y = pk2(a.z,a.w); o.z = pk2(b.x,b.y); o.w = pk2(b.z,b.w);
        *(uint4*)dst = o;
    }
}
// 8-wide bf16 dot-accumulate from two uint4s
__device__ __forceinline__ float dot8(uint4 uw, uint4 uh, float a){
    a = fmaf(bf2f((u16)uw.x),       bf2f((u16)uh.x),       a);
    a = fmaf(bf2f((u16)(uw.x>>16)), bf2f((u16)(uh.x>>16)), a);
    a = fmaf(bf2f((u16)uw.y),       bf2f((u16)uh.y),       a);
    a = fmaf(bf2f((u16)(uw.y>>16)), bf2f((u16)(uh.y>>16)), a);
    a = fmaf(bf2f((u16)uw.z),       bf2f((u16)uh.z),       a);
    a = fmaf(bf2f((u16)(uw.z>>16)), bf2f((u16)(uh.z>>16)), a);
    a = fmaf(bf2f((u16)uw.w),       bf2f((u16)uh.w),       a);
    a = fmaf(bf2f((u16)(uw.w>>16)), bf2f((u16)(uh.w>>16)), a);
    return a;
}

// ---------------- dtype probes ----------------
__device__ int probe_f_d(const void* p, int n_elems){
    const u32 w0 = ((const u32*)p)[0];
    if (w0 == 0x3F803F80u) return 1;
    if (w0 == 0x3F800000u) return 0;
    const u16* s = (const u16*)p;
    int m = n_elems < 128 ? n_elems : 128;
    for (int j = 0; j < m; j++) { float v = fabsf(bf2f(s[j])); if (v > 1e6f) return 0; }
    return 1;
}
__device__ int probe_i_d(const int* p){
    const u32* s = (const u32*)p;
    for (int j = 0; j < 128; j++) if (s[2*j+1] != 0u) return 0;
    return 1;
}
struct Ptrs27 { const void* p[27]; int n[27]; };
__global__ void __launch_bounds__(64)
probe_dtypes(Ptrs27 ptrs, int* __restrict__ flags)
{
    const int t = blockIdx.x;
    if (threadIdx.x != 0) return;
    flags[t] = (t == 2) ? probe_i_d((const int*)ptrs.p[t]) : probe_f_d(ptrs.p[t], ptrs.n[t]);
}

// weight [ri][co] -> bf16 [co][ri]
__global__ void __launch_bounds__(256)
repack_t(const void* __restrict__ src, u16* __restrict__ dst, int rows_in, int cols_out,
         const int* __restrict__ flags, int fidx)
{
    const int bf = flags[fidx];
    int i = blockIdx.x*256 + threadIdx.x;
    if (i < rows_in*cols_out) {
        int o = i % cols_out, r = i / cols_out;
        dst[o*rows_in + r] = bf ? ((const u16*)src)[i] : f2bf(((const float*)src)[i]);
    }
}

__global__ void __launch_bounds__(256)
prep_idx(const int* __restrict__ src, int* __restrict__ dst, int n, const int* __restrict__ flags)
{
    const int w64 = flags[2];
    int i = blockIdx.x*256 + threadIdx.x;
    if (i < n) dst[i] = w64 ? src[2*i] : src[i];
}

// ---- single-column-block GEMM pass (register-pressure-reduced) ----
// 48xKD (LDS, u16 pitch AP) @ W^T rows (pitch LD, col-offset KOFF), ONE 16-col
// block ct of this wave's 32-col range -> acc[3]. NOTE: the acc array passed
// here must be STATICALLY indexed at every call site (rule #20: runtime-indexed
// ext_vector arrays go to scratch -> 50+ MB spill traffic, R4 post-mortem).
template<int KD, int AP, int LD, int KOFF>
__device__ __forceinline__ void mfma3x1(const u16* As, const u16* __restrict__ wt, int tid, int ct, f32x4 acc[3])
{
    const int lane = tid & 63;
    const int l15  = lane & 15, q = lane >> 4;
    const int n0   = (tid >> 6) * 32 + ct*16;
    for (int k0 = 0; k0 < KD; k0 += 32) {
        const int ko = k0 + q*8;
        bf16x8 b0 = *(const bf16x8*)&wt[(size_t)(n0 + l15)*LD + KOFF + ko];
        bf16x8 a0 = *(const bf16x8*)&As[(l15     )*AP + ko];
        bf16x8 a1 = *(const bf16x8*)&As[(l15 + 16)*AP + ko];
        bf16x8 a2 = *(const bf16x8*)&As[(l15 + 32)*AP + ko];
        acc[0] = __builtin_amdgcn_mfma_f32_16x16x32_bf16(a0,b0,acc[0],0,0,0);
        acc[1] = __builtin_amdgcn_mfma_f32_16x16x32_bf16(a1,b0,acc[1],0,0,0);
        acc[2] = __builtin_amdgcn_mfma_f32_16x16x32_bf16(a2,b0,acc[2],0,0,0);
    }
}
// D[row=mt*16+(lane>>4)*4+r][col=(wave*32)+ct*16+(lane&15)]  (m89-verified C/D mapping)
template<bool BIAS>
__device__ __forceinline__ void epi_gelu1(const f32x4 acc[3], const void* __restrict__ bias, int bf,
                                          u16* Outs, int tid, int ct)
{
    const int lane = tid & 63, l15 = lane & 15, q = lane >> 4;
    const int col = (tid>>6)*32 + ct*16 + l15;
    float bv = 0.f;
    if constexpr (BIAS) bv = ldf(bias, col, bf);
    for (int mt = 0; mt < 3; mt++)
        for (int r = 0; r < 4; r++)
            Outs[(mt*16 + q*4 + r)*YPAD + col] = f2bf(gelu_ex(acc[mt][r] + bv));
}

// shared center GEMV: gv[c] = bias[c] + sum_k hc_bf16[k] * Wt[c*LD + k], k<128
// unroll BOUNDED at 4: full 16-iter unroll hoisted ~32 uint4 loads -> ~128 live
// VGPRs -> loop-resident scratch spill (R1-R4 post-mortems).
__device__ __forceinline__ void center_gemv(const u16* hcs, const u16* __restrict__ wt, int LD,
                                            const void* __restrict__ bias, int bfb,
                                            float* gvs, int tid)
{
    if (tid < H_) {
        const uint4* wr = (const uint4*)(wt + (size_t)tid*LD);
        const uint4* hh = (const uint4*)hcs;
        float a = 0.f;
#pragma unroll 4
        for (int i = 0; i < H_/8; i++) a = dot8(wr[i], hh[i], a);
        gvs[tid] = a + ldf(bias, tid, bfb);
    }
}

// ================= node kernel: MFMA =================
// X tile is only [h_E | hv_nb] (256 cols): the hv_ex block is row-constant, handled
// as a shared 128x128 GEMV folded into the MFMA C-initializer.
__global__ void __launch_bounds__(256, 3)
node_mfma(const void* __restrict__ hV, const void* __restrict__ hE, const int* __restrict__ idxn,
          const void* __restrict__ maskV, const void* __restrict__ maskAtt,
          const u16* __restrict__ w1t, const void* __restrict__ b1,
          const u16* __restrict__ w2t, const void* __restrict__ b2,
          const u16* __restrict__ w3t, const void* __restrict__ b3,
          const u16* __restrict__ wintt, const void* __restrict__ bin,
          const u16* __restrict__ woutt, const void* __restrict__ bout,
          const void* __restrict__ g1, const void* __restrict__ be1,
          const void* __restrict__ g2, const void* __restrict__ be2,
          const int* __restrict__ flags,
          float* __restrict__ outV, u16* __restrict__ wsVn)
{
    __shared__ __align__(16) u16 Xs[K_*XAP];     // 25,344 B; later aliased as Y2 tile
    __shared__ __align__(16) u16 Y1s[K_*YPAD];   // 13,056 B; later aliased as fp32 hid[512]
    __shared__ __align__(16) float scr[256];     // 1 KB union: {hcs,gvs} then {dhs,hvn1}
    __shared__ float matt[K_];
    __shared__ int   idxs[K_];
    __shared__ float stats[3];                   // mean, rstd, summask

    u16*   hcs  = (u16*)scr;                     // bytes    0..255  (center row, bf16)
    float* gvs  = scr + 64;                      // bytes  256..767  (center GEMV out)
    float* dhs  = scr;                           // bytes    0..511  (after GEMM3; hcs/gvs dead)
    float* hvn1 = scr + 128;                     // bytes 512..1023  (after LN1; gvs dead)

    const int bn  = blockIdx.x;
    const int b   = bn >> 10;
    const int tid = threadIdx.x;
    const int lane = tid & 63, w = tid >> 6;

    const int fHV = flags[0], fHE = flags[1], fMV = flags[3], fMA = flags[4];
    const int fb1 = flags[6], fb2 = flags[8], fb3 = flags[10];
    const int fbin = flags[18], fbout = flags[20];
    const int fg1 = flags[21], fbe1 = flags[22], fg2 = flags[23], fbe2 = flags[24];

    if (tid < K_) { idxs[tid] = idxn[bn*K_ + tid]; matt[tid] = ldf(maskAtt, (size_t)bn*K_ + tid, fMA); }
    __syncthreads();
    if (tid == 0) { float s=0.f; for (int k=0;k<K_;k++) s += matt[k]; stats[2] = s; }
    if (tid < 16) cp8(&hcs[tid*8], hV, (size_t)bn*H_ + (tid<<3), fHV);

    for (int u = tid; u < 768; u += 256) {
        const int row = u >> 4, c8 = (u & 15) << 3;
        cp8(&Xs[row*XAP + c8],      hE, ((size_t)bn*K_ + row)*H_ + c8, fHE);
        cp8(&Xs[row*XAP + H_ + c8], hV, ((size_t)b*N_ + idxs[row])*H_ + c8, fHV);
    }
    __syncthreads();

    // shared center GEMV (W1 rows 0..127), bias folded
    center_gemv(hcs, w1t, CAT_, b1, fb1, gvs, tid);
    __syncthreads();

    const int l15 = lane & 15, q = lane >> 4, n0 = w*32;

    // ---- GEMM1: two single-col-block passes (register-pressure split) ----
#pragma unroll 1
    for (int ct = 0; ct < 2; ct++) {
        f32x4 acc[3];
        const float g = gvs[n0 + ct*16 + l15];
        for (int mt=0; mt<3; mt++) for (int r=0; r<4; r++) acc[mt][r] = g;
        mfma3x1<256, XAP, CAT_, H_>(Xs, w1t, tid, ct, acc);   // W1 rows 128..383
        epi_gelu1<false>(acc, nullptr, 0, Y1s, tid, ct);
    }
    __syncthreads();                 // Y1 visible; everyone done reading Xs

    u16* Y2s = Xs;                   // alias X region as Y2 tile (pitch YPAD)
#pragma unroll 1
    for (int ct = 0; ct < 2; ct++) {
        f32x4 acc[3] = {fzero(), fzero(), fzero()};
        mfma3x1<H_, YPAD, H_, 0>(Y1s, w2t, tid, ct, acc);
        epi_gelu1<true>(acc, b2, fb2, Y2s, tid, ct);
    }
    __syncthreads();

#pragma unroll 1
    for (int ct = 0; ct < 2; ct++) {
        f32x4 acc[3] = {fzero(), fzero(), fzero()};
        mfma3x1<H_, YPAD, H_, 0>(Y2s, w3t, tid, ct, acc);
        // masked sum over K rows -> dh (this wave's 16-col block ct)
        float s0 = 0.f;
        for (int mt=0; mt<3; mt++)
            for (int r=0; r<4; r++)
                s0 += acc[mt][r]*matt[mt*16 + q*4 + r];
        s0 += __shfl_xor(s0,16); s0 += __shfl_xor(s0,32);
        if (q == 0) {
            const int col = n0 + ct*16 + l15;
            dhs[col] = (s0 + ldf(b3, col, fb3)*stats[2]) * INV_SCALE;
        }
    }
    __syncthreads();

    // ---- LN1 (h = hV + dh recomputed from global) ----
    if (w == 0) {
        float a = ldf(hV, (size_t)bn*H_ + lane,      fHV) + dhs[lane];
        float c = ldf(hV, (size_t)bn*H_ + lane + 64, fHV) + dhs[lane+64];
        float s = a + c, ss = a*a + c*c;
        for (int off=32; off>0; off>>=1) { s += __shfl_xor(s,off); ss += __shfl_xor(ss,off); }
        if (lane == 0) { float m = s*(1.f/H_); stats[0]=m; stats[1]=rsqrtf(ss*(1.f/H_)-m*m+EPS_); }
    }
    __syncthreads();
    if (tid < H_) {
        float h = ldf(hV, (size_t)bn*H_ + tid, fHV) + dhs[tid];
        hvn1[tid] = (h - stats[0])*stats[1]*ldf(g1,tid,fg1) + ldf(be1,tid,fbe1);
    }
    __syncthreads();

    // ---- FFN (bf16 weight rows, uint4 loads; unroll bounded for reg pressure) ----
    float* hid = (float*)Y1s;        // alias Y1 region (dead) as fp32 hid[512]
    for (int j = tid; j < FF_; j += 256) {
        const uint4* wr = (const uint4*)(wintt + (size_t)j*H_);
        float a = 0.f;
#pragma unroll 4
        for (int i = 0; i < H_/8; i++) {
            uint4 u = wr[i];
            a += hvn1[8*i+0]*bf2f((u16)u.x) + hvn1[8*i+1]*bf2f((u16)(u.x>>16));
            a += hvn1[8*i+2]*bf2f((u16)u.y) + hvn1[8*i+3]*bf2f((u16)(u.y>>16));
            a += hvn1[8*i+4]*bf2f((u16)u.z) + hvn1[8*i+5]*bf2f((u16)(u.z>>16));
            a += hvn1[8*i+6]*bf2f((u16)u.w) + hvn1[8*i+7]*bf2f((u16)(u.w>>16));
        }
        hid[j] = gelu_ex(a + ldf(bin, j, fbin));
    }
    __syncthreads();
    if (tid < H_) {
        const uint4* wr = (const uint4*)(woutt + (size_t)tid*FF_);
        float a = 0.f;
#pragma unroll 4
        for (int i = 0; i < FF_/8; i++) {
            uint4 u = wr[i];
            a += hid[8*i+0]*bf2f((u16)u.x) + hid[8*i+1]*bf2f((u16)(u.x>>16));
            a += hid[8*i+2]*bf2f((u16)u.y) + hid[8*i+3]*bf2f((u16)(u.y>>16));
            a += hid[8*i+4]*bf2f((u16)u.z) + hid[8*i+5]*bf2f((u16)(u.z>>16));
            a += hid[8*i+6]*bf2f((u16)u.w) + hid[8*i+7]*bf2f((u16)(u.w>>16));
        }
        dhs[tid] = hvn1[tid] + a + ldf(bout, tid, fbout);   // dhs reused as h2 buffer
    }
    __syncthreads();
    // ---- LN2 + mask ----
    if (w == 0) {
        float a = dhs[lane], c = dhs[lane+64];
        float s = a + c, ss = a*a + c*c;
        for (int off=32; off>0; off>>=1) { s += __shfl_xor(s,off); ss += __shfl_xor(ss,off); }
        if (lane == 0) { float m = s*(1.f/H_); stats[0]=m; stats[1]=rsqrtf(ss*(1.f/H_)-m*m+EPS_); }
    }
    __syncthreads();
    if (tid < H_) {
        float v = (dhs[tid]-stats[0])*stats[1]*ldf(g2,tid,fg2) + ldf(be2,tid,fbe2);
        v *= ldf(maskV, bn, fMV);
        outV[(size_t)bn*H_ + tid] = v;          // fp32 output
        wsVn[(size_t)bn*H_ + tid] = f2bf(v);    // bf16 copy for edge staging
    }
}

// ================= edge kernel: MFMA =================
__global__ void __launch_bounds__(256, 3)
edge_mfma(const u16* __restrict__ wsVn, const void* __restrict__ hE, const int* __restrict__ idxn,
          const u16* __restrict__ w11t, const void* __restrict__ b11,
          const u16* __restrict__ w12t, const void* __restrict__ b12,
          const u16* __restrict__ w13t, const void* __restrict__ b13,
          const void* __restrict__ g3, const void* __restrict__ be3,
          const int* __restrict__ flags,
          float* __restrict__ outE)
{
    __shared__ __align__(16) u16 Xs[K_*XAP];    // 25,344 B; aliased as Y2, then fp32 M [48][132]
    __shared__ __align__(16) u16 Y1s[K_*YPAD];
    __shared__ __align__(16) float scr[192];    // hcs (256 B) + gvs (512 B)
    __shared__ int idxs[K_];

    u16*   hcs = (u16*)scr;
    float* gvs = scr + 64;

    const int bn  = blockIdx.x;
    const int b   = bn >> 10;
    const int tid = threadIdx.x;
    const int lane = tid & 63, w = tid >> 6;

    const int fHE = flags[1];
    const int fb11 = flags[12], fb12 = flags[14], fb13 = flags[16];
    const int fg3 = flags[25], fbe3 = flags[26];

    if (tid < K_) idxs[tid] = idxn[bn*K_ + tid];
    __syncthreads();

    const u16* hVb = wsVn + (size_t)b*N_*H_;
    if (tid < 16) *(uint4*)&hcs[tid*8] = *(const uint4*)&wsVn[(size_t)bn*H_ + (tid<<3)];
    for (int u = tid; u < 768; u += 256) {
        const int row = u >> 4, c8 = (u & 15) << 3;
        cp8(&Xs[row*XAP + c8], hE, ((size_t)bn*K_ + row)*H_ + c8, fHE);
        *(uint4*)&Xs[row*XAP + H_ + c8] = *(const uint4*)&hVb[(size_t)idxs[row]*H_ + c8];
    }
    __syncthreads();

    center_gemv(hcs, w11t, CAT_, b11, fb11, gvs, tid);
    __syncthreads();

    const int l15 = lane & 15, q = lane >> 4, n0 = w*32;

#pragma unroll 1
    for (int ct = 0; ct < 2; ct++) {
        f32x4 acc[3];
        const float g = gvs[n0 + ct*16 + l15];
        for (int mt=0; mt<3; mt++) for (int r=0; r<4; r++) acc[mt][r] = g;
        mfma3x1<256, XAP, CAT_, H_>(Xs, w11t, tid, ct, acc);
        epi_gelu1<false>(acc, nullptr, 0, Y1s, tid, ct);
    }
    __syncthreads();

    u16* Y2s = Xs;
#pragma unroll 1
    for (int ct = 0; ct < 2; ct++) {
        f32x4 acc[3] = {fzero(), fzero(), fzero()};
        mfma3x1<H_, YPAD, H_, 0>(Y1s, w12t, tid, ct, acc);
        epi_gelu1<true>(acc, b12, fb12, Y2s, tid, ct);
    }
    __syncthreads();

    // GEMM3: NAMED static accumulators. R3/R4 used acc3[2][3] indexed by the
    // runtime ct of an unroll-1 loop -> rule #20 scratch allocation: every MFMA
    // accumulated through local memory (96 B/thread = ~50 MB HBM round-trip per
    // dispatch; WRITE_SIZE 96 MB, cold-dispatch 212 µs at 1.5% occupancy).
    // Both passes must finish BEFORE Xs is overwritten as Ms (Y2s aliases Xs).
    f32x4 accA[3] = {fzero(), fzero(), fzero()};
    f32x4 accB[3] = {fzero(), fzero(), fzero()};
    mfma3x1<H_, YPAD, H_, 0>(Y2s, w13t, tid, 0, accA);
    mfma3x1<H_, YPAD, H_, 0>(Y2s, w13t, tid, 1, accB);
    __syncthreads();                  // all layer-3 reads of Y2 (Xs) done
    float* Ms = (float*)Xs;           // fp32 M tile [48][MPAD] — exactly fits 48*264 u16
    {
        const int colA = n0 + l15;
        const float bvA = ldf(b13, colA, fb13);
        for (int mt=0; mt<3; mt++)
            for (int r=0; r<4; r++)
                Ms[(mt*16 + q*4 + r)*MPAD + colA] = accA[mt][r] + bvA;
        const int colB = n0 + 16 + l15;
        const float bvB = ldf(b13, colB, fb13);
        for (int mt=0; mt<3; mt++)
            for (int r=0; r<4; r++)
                Ms[(mt*16 + q*4 + r)*MPAD + colB] = accB[mt][r] + bvB;
    }
    __syncthreads();

    // h_En = LN(h_E + M), one wave per row, fp32 store
    for (int row = w; row < K_; row += 4) {
        const size_t e0 = ((size_t)bn*K_ + row)*H_;
        float v0 = ldf(hE, e0 + lane,      fHE) + Ms[row*MPAD + lane];
        float v1 = ldf(hE, e0 + lane + 64, fHE) + Ms[row*MPAD + lane + 64];
        float s = v0+v1, ss = v0*v0+v1*v1;
        for (int off=32; off>0; off>>=1) { s += __shfl_xor(s,off); ss += __shfl_xor(ss,off); }
        const float m = s*(1.f/H_);
        const float rstd = rsqrtf(ss*(1.f/H_) - m*m + EPS_);
        outE[e0 + lane]      = (v0-m)*rstd*ldf(g3,lane,fg3)    + ldf(be3,lane,fbe3);
        outE[e0 + lane + 64] = (v1-m)*rstd*ldf(g3,lane+64,fg3) + ldf(be3,lane+64,fbe3);
    }
}

extern "C" void kernel_launch(void* const* d_in, const int* in_sizes, int n_in,
                              void* d_out, int out_size, void* d_ws, size_t ws_size,
                              hipStream_t stream)
{
    const void* hV      = d_in[0];
    const void* hE      = d_in[1];
    const int*  Eidx    = (const int*)d_in[2];
    const void* maskV   = d_in[3];
    const void* maskAtt = d_in[4];
    const void* W1w  = d_in[5];  const void* W1b  = d_in[6];
    const void* W2w  = d_in[7];  const void* W2b  = d_in[8];
    const void* W3w  = d_in[9];  const void* W3b  = d_in[10];
    const void* W11w = d_in[11]; const void* W11b = d_in[12];
    const void* W12w = d_in[13]; const void* W12b = d_in[14];
    const void* W13w = d_in[15]; const void* W13b = d_in[16];
    const void* Winw = d_in[17]; const void* Winb = d_in[18];
    const void* Woutw= d_in[19]; const void* Woutb= d_in[20];
    const void* ln1g = d_in[21]; const void* ln1b = d_in[22];
    const void* ln2g = d_in[23]; const void* ln2b = d_in[24];
    const void* ln3g = d_in[25]; const void* ln3b = d_in[26];

    // ws layout (u16 units)
    u16* ws    = (u16*)d_ws;
    u16* w1t   = ws;                        // 128*384
    u16* w2t   = w1t   + 128*384;           // 128*128
    u16* w3t   = w2t   + 128*128;
    u16* w11t  = w3t   + 128*128;           // 128*384
    u16* w12t  = w11t  + 128*384;
    u16* w13t  = w12t  + 128*128;
    u16* wintt = w13t  + 128*128;           // 512*128
    u16* woutt = wintt + 512*128;           // 128*512
    int* idxn  = (int*)(woutt + 128*512);   // 98304 int32
    u16* wsVn  = (u16*)(idxn + B_*N_*K_);   // 262144 bf16
    int* flags = (int*)(wsVn + B_*N_*H_);   // 27 ints

    Ptrs27 P;
    for (int i = 0; i < 27; i++) { P.p[i] = d_in[i]; P.n[i] = in_sizes[i]; }
    hipLaunchKernelGGL(probe_dtypes, dim3(27), dim3(64), 0, stream, P, flags);

    auto T = [&](const void* src, u16* dst, int ri, int co, int fidx) {
        hipLaunchKernelGGL(repack_t, dim3((ri*co+255)/256), dim3(256), 0, stream, src, dst, ri, co, flags, fidx);
    };
    T(W1w,  w1t,  384, 128, 5);
    T(W2w,  w2t,  128, 128, 7);
    T(W3w,  w3t,  128, 128, 9);
    T(W11w, w11t, 384, 128, 11);
    T(W12w, w12t, 128, 128, 13);
    T(W13w, w13t, 128, 128, 15);
    T(Winw, wintt, 128, 512, 17);
    T(Woutw,woutt, 512, 128, 19);
    hipLaunchKernelGGL(prep_idx, dim3((B_*N_*K_+255)/256), dim3(256), 0, stream, Eidx, idxn, B_*N_*K_, flags);

    float* outV = (float*)d_out;
    float* outE = outV + (size_t)B_*N_*H_;

    hipLaunchKernelGGL(node_mfma, dim3(B_*N_), dim3(256), 0, stream,
                       hV, hE, idxn, maskV, maskAtt,
                       w1t, W1b, w2t, W2b, w3t, W3b,
                       wintt, Winb, woutt, Woutb,
                       ln1g, ln1b, ln2g, ln2b,
                       flags, outV, wsVn);
    hipLaunchKernelGGL(edge_mfma, dim3(B_*N_), dim3(256), 0, stream,
                       wsVn, hE, idxn,
                       w11t, W11b, w12t, W12b, w13t, W13b,
                       ln3g, ln3b, flags, outE);
}

// Round 6
// 325.953 us; speedup vs baseline: 1.3493x; 1.1566x over previous
//
#include <hip/hip_runtime.h>
#include <cstdint>
#include <cstddef>

typedef unsigned short u16;
typedef unsigned int   u32;
typedef __bf16  bf16x8 __attribute__((ext_vector_type(8)));
typedef float   f32x4  __attribute__((ext_vector_type(4)));

#define B_    2
#define N_    1024
#define K_    48
#define H_    128
#define CAT_  384
#define FF_   512
#define XAP   264   // bf16 row pitch for reduced X tile (256+8)
#define YPAD  136   // bf16 row pitch for 128-col tiles (128+8)
#define HIDP  520   // bf16 row pitch for ffn hid tile (512+8)
#define MPAD  132   // fp32 row pitch for 128-col fp32 tiles
#define EPS_  1e-5f
#define INV_SCALE (1.0f/48.0f)

__device__ __forceinline__ float bf2f(u16 u){ u32 x=((u32)u)<<16; float f; __builtin_memcpy(&f,&x,4); return f; }
__device__ __forceinline__ u16 f2bf(float f){ u32 x; __builtin_memcpy(&x,&f,4); x=(x+0x7FFFu+((x>>16)&1u))>>16; return (u16)x; }
__device__ __forceinline__ u32 pk2(float lo, float hi){ return (u32)f2bf(lo) | ((u32)f2bf(hi)<<16); }

// Branch-free exact-GELU: erf via Abramowitz-Stegun 7.1.26 (|err|<=1.5e-7).
__device__ __forceinline__ float gelu_ex(float x){
    const float s = x * 0.7071067811865476f;
    const float a = fabsf(s);
    const float t = __builtin_amdgcn_rcpf(__builtin_fmaf(0.3275911f, a, 1.0f));
    float p = __builtin_fmaf(1.061405429f, t, -1.453152027f);
    p = __builtin_fmaf(p, t,  1.421413741f);
    p = __builtin_fmaf(p, t, -0.284496736f);
    p = __builtin_fmaf(p, t,  0.254829592f);
    p *= t;
    const float e = __expf(-s*s);
    const float erfa = __builtin_fmaf(-p, e, 1.0f);
    const float erf  = __builtin_copysignf(erfa, s);
    return 0.5f*x*(1.0f+erf);
}
__device__ __forceinline__ f32x4 fzero(){ f32x4 v; v[0]=0.f; v[1]=0.f; v[2]=0.f; v[3]=0.f; return v; }

__device__ __forceinline__ float ldf(const void* p, size_t i, int bf){
    return bf ? bf2f(((const u16*)p)[i]) : ((const float*)p)[i];
}
// 8 consecutive elems -> bf16 LDS (dtype-aware)
__device__ __forceinline__ void cp8(u16* dst, const void* src, size_t eoff, int bf){
    if (bf) { *(uint4*)dst = *(const uint4*)((const u16*)src + eoff); }
    else {
        const float4* s = (const float4*)((const float*)src + eoff);
        float4 a = s[0], b = s[1];
        uint4 o; o.x = pk2(a.x,a.y); o.y = pk2(a.z,a.w); o.z = pk2(b.x,b.y); o.w = pk2(b.z,b.w);
        *(uint4*)dst = o;
    }
}

// ---------------- dtype probes ----------------
__device__ int probe_f_d(const void* p, int n_elems){
    const u32 w0 = ((const u32*)p)[0];
    if (w0 == 0x3F803F80u) return 1;
    if (w0 == 0x3F800000u) return 0;
    const u16* s = (const u16*)p;
    int m = n_elems < 128 ? n_elems : 128;
    for (int j = 0; j < m; j++) { float v = fabsf(bf2f(s[j])); if (v > 1e6f) return 0; }
    return 1;
}
__device__ int probe_i_d(const int* p){
    const u32* s = (const u32*)p;
    for (int j = 0; j < 128; j++) if (s[2*j+1] != 0u) return 0;
    return 1;
}
struct Ptrs27 { const void* p[27]; int n[27]; };
__global__ void __launch_bounds__(64)
probe_dtypes(Ptrs27 ptrs, int* __restrict__ flags)
{
    const int t = blockIdx.x;
    if (threadIdx.x != 0) return;
    flags[t] = (t == 2) ? probe_i_d((const int*)ptrs.p[t]) : probe_f_d(ptrs.p[t], ptrs.n[t]);
}

// weight [ri][co] -> bf16 [co][ri]
__global__ void __launch_bounds__(256)
repack_t(const void* __restrict__ src, u16* __restrict__ dst, int rows_in, int cols_out,
         const int* __restrict__ flags, int fidx)
{
    const int bf = flags[fidx];
    int i = blockIdx.x*256 + threadIdx.x;
    if (i < rows_in*cols_out) {
        int o = i % cols_out, r = i / cols_out;
        dst[o*rows_in + r] = bf ? ((const u16*)src)[i] : f2bf(((const float*)src)[i]);
    }
}

__global__ void __launch_bounds__(256)
prep_idx(const int* __restrict__ src, int* __restrict__ dst, int n, const int* __restrict__ flags)
{
    const int w64 = flags[2];
    int i = blockIdx.x*256 + threadIdx.x;
    if (i < n) dst[i] = w64 ? src[2*i] : src[i];
}

// ---- single-column-block GEMM pass (register-pressure-reduced) ----
// 48xKD (LDS, u16 pitch AP) @ W^T rows (pitch LD, col-offset KOFF), ONE 16-col
// block ct of this wave's 32-col range -> acc[3]. acc must be statically indexed
// at call sites (rule #20; R4 post-mortem).
template<int KD, int AP, int LD, int KOFF>
__device__ __forceinline__ void mfma3x1(const u16* As, const u16* __restrict__ wt, int tid, int ct, f32x4 acc[3])
{
    const int lane = tid & 63;
    const int l15  = lane & 15, q = lane >> 4;
    const int n0   = (tid >> 6) * 32 + ct*16;
    for (int k0 = 0; k0 < KD; k0 += 32) {
        const int ko = k0 + q*8;
        bf16x8 b0 = *(const bf16x8*)&wt[(size_t)(n0 + l15)*LD + KOFF + ko];
        bf16x8 a0 = *(const bf16x8*)&As[(l15     )*AP + ko];
        bf16x8 a1 = *(const bf16x8*)&As[(l15 + 16)*AP + ko];
        bf16x8 a2 = *(const bf16x8*)&As[(l15 + 32)*AP + ko];
        acc[0] = __builtin_amdgcn_mfma_f32_16x16x32_bf16(a0,b0,acc[0],0,0,0);
        acc[1] = __builtin_amdgcn_mfma_f32_16x16x32_bf16(a1,b0,acc[1],0,0,0);
        acc[2] = __builtin_amdgcn_mfma_f32_16x16x32_bf16(a2,b0,acc[2],0,0,0);
    }
}
// D[row=mt*16+(lane>>4)*4+r][col=(wave*32)+ct*16+(lane&15)]  (m89-verified C/D mapping)
template<bool BIAS>
__device__ __forceinline__ void epi_gelu1(const f32x4 acc[3], const void* __restrict__ bias, int bf,
                                          u16* Outs, int tid, int ct)
{
    const int lane = tid & 63, l15 = lane & 15, q = lane >> 4;
    const int col = (tid>>6)*32 + ct*16 + l15;
    float bv = 0.f;
    if constexpr (BIAS) bv = ldf(bias, col, bf);
    for (int mt = 0; mt < 3; mt++)
        for (int r = 0; r < 4; r++)
            Outs[(mt*16 + q*4 + r)*YPAD + col] = f2bf(gelu_ex(acc[mt][r] + bv));
}

// ================= pre_gv1: gv1 = bf16(hV) @ W1[0:128,:] + b1, all 2048 rows =================
// 16-row MFMA tiles: replaces the per-block center_gemv (96 KB of weight traffic
// per node-block, 2048x) with 128 blocks reading W1-top once each.
__global__ void __launch_bounds__(256, 2)
pre_gv1(const void* __restrict__ hV, const u16* __restrict__ w1t, const void* __restrict__ b1,
        const int* __restrict__ flags, float* __restrict__ gv1f)
{
    __shared__ __align__(16) u16 Ah[16*YPAD];
    const int r0 = blockIdx.x*16;
    const int tid = threadIdx.x, lane = tid & 63, w = tid >> 6;
    const int l15 = lane & 15, q = lane >> 4;
    const int fHV = flags[0], fb1 = flags[6];

    { const int row = tid >> 4, c8 = (tid & 15) << 3;
      cp8(&Ah[row*YPAD + c8], hV, (size_t)(r0+row)*H_ + c8, fHV); }
    __syncthreads();

    const int n0 = w*32;
    f32x4 a0, a1;
    { float b0v = ldf(b1, n0+l15, fb1), b1v = ldf(b1, n0+16+l15, fb1);
      for (int r=0;r<4;r++){ a0[r]=b0v; a1[r]=b1v; } }
#pragma unroll 1
    for (int k0 = 0; k0 < H_; k0 += 32) {
        const int ko = k0 + q*8;
        bf16x8 a  = *(const bf16x8*)&Ah[l15*YPAD + ko];
        bf16x8 b0 = *(const bf16x8*)&w1t[(size_t)(n0 + l15)*CAT_ + ko];
        bf16x8 b1 = *(const bf16x8*)&w1t[(size_t)(n0 + 16 + l15)*CAT_ + ko];
        a0 = __builtin_amdgcn_mfma_f32_16x16x32_bf16(a,b0,a0,0,0,0);
        a1 = __builtin_amdgcn_mfma_f32_16x16x32_bf16(a,b1,a1,0,0,0);
    }
    for (int r=0;r<4;r++) {
        gv1f[(size_t)(r0 + q*4 + r)*H_ + n0 + l15]      = a0[r];
        gv1f[(size_t)(r0 + q*4 + r)*H_ + n0 + 16 + l15] = a1[r];
    }
}

// ================= node kernel: message + LN1 only =================
// FFN/LN2 hoisted to ffn_fused (weight amortization); center GEMV hoisted to
// pre_gv1. Chain: stage -> G1 -> G2 -> G3+reduce -> LN1 -> hvn1f. ~6 barriers.
__global__ void __launch_bounds__(256, 3)
node_mfma(const void* __restrict__ hV, const void* __restrict__ hE, const int* __restrict__ idxn,
          const void* __restrict__ maskAtt,
          const u16* __restrict__ w1t,
          const u16* __restrict__ w2t, const void* __restrict__ b2,
          const u16* __restrict__ w3t, const void* __restrict__ b3,
          const void* __restrict__ g1, const void* __restrict__ be1,
          const float* __restrict__ gv1f,
          const int* __restrict__ flags,
          float* __restrict__ hvn1f)
{
    __shared__ __align__(16) u16 Xs[K_*XAP];     // X tile; later aliased as Y2
    __shared__ __align__(16) u16 Y1s[K_*YPAD];
    __shared__ float dhs[H_];
    __shared__ float matt[K_];
    __shared__ int   idxs[K_];
    __shared__ float stats[3];                   // mean, rstd, summask

    const int bn  = blockIdx.x;
    const int b   = bn >> 10;
    const int tid = threadIdx.x;
    const int lane = tid & 63, w = tid >> 6;

    const int fHV = flags[0], fHE = flags[1], fMA = flags[4];
    const int fb2 = flags[8], fb3 = flags[10];
    const int fg1 = flags[21], fbe1 = flags[22];

    if (tid < K_) { idxs[tid] = idxn[bn*K_ + tid]; matt[tid] = ldf(maskAtt, (size_t)bn*K_ + tid, fMA); }
    __syncthreads();
    if (tid == 0) { float s=0.f; for (int k=0;k<K_;k++) s += matt[k]; stats[2] = s; }

    for (int u = tid; u < 768; u += 256) {
        const int row = u >> 4, c8 = (u & 15) << 3;
        cp8(&Xs[row*XAP + c8],      hE, ((size_t)bn*K_ + row)*H_ + c8, fHE);
        cp8(&Xs[row*XAP + H_ + c8], hV, ((size_t)b*N_ + idxs[row])*H_ + c8, fHV);
    }
    __syncthreads();

    const int l15 = lane & 15, q = lane >> 4, n0 = w*32;

    // ---- GEMM1: C-init from gv1 (center term + b1, precomputed) ----
#pragma unroll 1
    for (int ct = 0; ct < 2; ct++) {
        f32x4 acc[3];
        const float g = gv1f[(size_t)bn*H_ + n0 + ct*16 + l15];
        for (int mt=0; mt<3; mt++) for (int r=0; r<4; r++) acc[mt][r] = g;
        mfma3x1<256, XAP, CAT_, H_>(Xs, w1t, tid, ct, acc);   // W1 rows 128..383
        epi_gelu1<false>(acc, nullptr, 0, Y1s, tid, ct);
    }
    __syncthreads();

    u16* Y2s = Xs;
#pragma unroll 1
    for (int ct = 0; ct < 2; ct++) {
        f32x4 acc[3] = {fzero(), fzero(), fzero()};
        mfma3x1<H_, YPAD, H_, 0>(Y1s, w2t, tid, ct, acc);
        epi_gelu1<true>(acc, b2, fb2, Y2s, tid, ct);
    }
    __syncthreads();

#pragma unroll 1
    for (int ct = 0; ct < 2; ct++) {
        f32x4 acc[3] = {fzero(), fzero(), fzero()};
        mfma3x1<H_, YPAD, H_, 0>(Y2s, w3t, tid, ct, acc);
        float s0 = 0.f;
        for (int mt=0; mt<3; mt++)
            for (int r=0; r<4; r++)
                s0 += acc[mt][r]*matt[mt*16 + q*4 + r];
        s0 += __shfl_xor(s0,16); s0 += __shfl_xor(s0,32);
        if (q == 0) {
            const int col = n0 + ct*16 + l15;
            dhs[col] = (s0 + ldf(b3, col, fb3)*stats[2]) * INV_SCALE;
        }
    }
    __syncthreads();

    // ---- LN1 -> hvn1f (fp32 ws; ffn_fused consumes) ----
    if (w == 0) {
        float a = ldf(hV, (size_t)bn*H_ + lane,      fHV) + dhs[lane];
        float c = ldf(hV, (size_t)bn*H_ + lane + 64, fHV) + dhs[lane+64];
        float s = a + c, ss = a*a + c*c;
        for (int off=32; off>0; off>>=1) { s += __shfl_xor(s,off); ss += __shfl_xor(ss,off); }
        if (lane == 0) { float m = s*(1.f/H_); stats[0]=m; stats[1]=rsqrtf(ss*(1.f/H_)-m*m+EPS_); }
    }
    __syncthreads();
    if (tid < H_) {
        float h = ldf(hV, (size_t)bn*H_ + tid, fHV) + dhs[tid];
        hvn1f[(size_t)bn*H_ + tid] = (h - stats[0])*stats[1]*ldf(g1,tid,fg1) + ldf(be1,tid,fbe1);
    }
}

// ================= ffn_fused: FFN + LN2 + mask + gv11, 16 rows/block =================
// Batched GEMM form amortizes Win/Wout/W11-top across 16 rows (vs 1 row before:
// 512 MB -> 32 MB of FFN weight traffic). Also emits gv11 (edge center term).
__global__ void __launch_bounds__(256, 2)
ffn_fused(const float* __restrict__ hvn1f, const void* __restrict__ maskV,
          const u16* __restrict__ wintt, const void* __restrict__ bin,
          const u16* __restrict__ woutt, const void* __restrict__ bout,
          const u16* __restrict__ w11t, const void* __restrict__ b11,
          const void* __restrict__ g2, const void* __restrict__ be2,
          const int* __restrict__ flags,
          float* __restrict__ outV, u16* __restrict__ wsVn, float* __restrict__ gv11f)
{
    __shared__ __align__(16) float hvf[16*H_];     // fp32 hvn1 (residual)
    __shared__ __align__(16) u16   Xh[16*YPAD];    // bf16 A-tile of hvn1
    __shared__ __align__(16) u16   hid[16*HIDP];   // bf16 hidden 16x512
    __shared__ __align__(16) float h2f[16*MPAD];   // fp32 pre-LN2
    __shared__ __align__(16) u16   h2b[16*YPAD];   // bf16 LN2 out (gv11 A-tile)

    const int r0  = blockIdx.x*16;
    const int tid = threadIdx.x, lane = tid & 63, w = tid >> 6;
    const int l15 = lane & 15, q = lane >> 4;
    const int fMV = flags[3], fbin = flags[18], fbout = flags[20];
    const int fb11 = flags[12], fg2 = flags[23], fbe2 = flags[24];

    {   // stage hvn1 rows (fp32 + bf16)
        const int row = tid >> 4, c8 = (tid & 15) << 3;
        const float4* s = (const float4*)&hvn1f[(size_t)(r0+row)*H_ + c8];
        float4 a = s[0], b = s[1];
        *(float4*)&hvf[row*H_ + c8]     = a;
        *(float4*)&hvf[row*H_ + c8 + 4] = b;
        uint4 o; o.x = pk2(a.x,a.y); o.y = pk2(a.z,a.w); o.z = pk2(b.x,b.y); o.w = pk2(b.z,b.w);
        *(uint4*)&Xh[row*YPAD + c8] = o;
    }
    __syncthreads();

    // ---- GEMM1: hid[16x512]; wave w owns cols w*128..+127 (8 ct blocks) ----
    {
        f32x4 acc[8];
#pragma unroll
        for (int ct = 0; ct < 8; ct++) {
            const float bv = ldf(bin, w*128 + ct*16 + l15, fbin);
            for (int r=0;r<4;r++) acc[ct][r] = bv;
        }
#pragma unroll 1
        for (int k0 = 0; k0 < H_; k0 += 32) {
            const int ko = k0 + q*8;
            bf16x8 a = *(const bf16x8*)&Xh[l15*YPAD + ko];
#pragma unroll
            for (int ct = 0; ct < 8; ct++) {
                bf16x8 b = *(const bf16x8*)&wintt[(size_t)(w*128 + ct*16 + l15)*H_ + ko];
                acc[ct] = __builtin_amdgcn_mfma_f32_16x16x32_bf16(a,b,acc[ct],0,0,0);
            }
        }
#pragma unroll
        for (int ct = 0; ct < 8; ct++) {
            const int col = w*128 + ct*16 + l15;
            for (int r=0;r<4;r++)
                hid[(q*4 + r)*HIDP + col] = f2bf(gelu_ex(acc[ct][r]));
        }
    }
    __syncthreads();

    // ---- GEMM2: out 16x128; wave w owns 32 cols; + bout + fp32 residual ----
    {
        const int n0 = w*32;
        f32x4 c0 = fzero(), c1 = fzero();
#pragma unroll 1
        for (int k0 = 0; k0 < FF_; k0 += 32) {
            const int ko = k0 + q*8;
            bf16x8 a  = *(const bf16x8*)&hid[l15*HIDP + ko];
            bf16x8 b0 = *(const bf16x8*)&woutt[(size_t)(n0 + l15)*FF_ + ko];
            bf16x8 b1 = *(const bf16x8*)&woutt[(size_t)(n0 + 16 + l15)*FF_ + ko];
            c0 = __builtin_amdgcn_mfma_f32_16x16x32_bf16(a,b0,c0,0,0,0);
            c1 = __builtin_amdgcn_mfma_f32_16x16x32_bf16(a,b1,c1,0,0,0);
        }
        const float bo0 = ldf(bout, n0+l15, fbout), bo1 = ldf(bout, n0+16+l15, fbout);
        for (int r=0;r<4;r++) {
            const int row = q*4 + r;
            h2f[row*MPAD + n0+l15]    = c0[r] + bo0 + hvf[row*H_ + n0+l15];
            h2f[row*MPAD + n0+16+l15] = c1[r] + bo1 + hvf[row*H_ + n0+16+l15];
        }
    }
    __syncthreads();

    // ---- LN2 + mask; rows w, w+4, w+8, w+12 per wave ----
    for (int row = w; row < 16; row += 4) {
        float v0 = h2f[row*MPAD + lane], v1 = h2f[row*MPAD + lane + 64];
        float s = v0+v1, ss = v0*v0+v1*v1;
        for (int off=32; off>0; off>>=1) { s += __shfl_xor(s,off); ss += __shfl_xor(ss,off); }
        const float m = s*(1.f/H_);
        const float rstd = rsqrtf(ss*(1.f/H_) - m*m + EPS_);
        const float mk = ldf(maskV, r0+row, fMV);
        const float o0 = ((v0-m)*rstd*ldf(g2,lane,fg2)    + ldf(be2,lane,fbe2))    * mk;
        const float o1 = ((v1-m)*rstd*ldf(g2,lane+64,fg2) + ldf(be2,lane+64,fbe2)) * mk;
        outV[(size_t)(r0+row)*H_ + lane]      = o0;
        outV[(size_t)(r0+row)*H_ + lane + 64] = o1;
        const u16 u0 = f2bf(o0), u1 = f2bf(o1);
        wsVn[(size_t)(r0+row)*H_ + lane]      = u0;
        wsVn[(size_t)(r0+row)*H_ + lane + 64] = u1;
        h2b[row*YPAD + lane]      = u0;
        h2b[row*YPAD + lane + 64] = u1;
    }
    __syncthreads();

    // ---- GEMM3: gv11 = h2b @ W11[0:128,:] + b11 (edge center term) ----
    {
        const int n0 = w*32;
        f32x4 d0, d1;
        { float b0v = ldf(b11, n0+l15, fb11), b1v = ldf(b11, n0+16+l15, fb11);
          for (int r=0;r<4;r++){ d0[r]=b0v; d1[r]=b1v; } }
#pragma unroll 1
        for (int k0 = 0; k0 < H_; k0 += 32) {
            const int ko = k0 + q*8;
            bf16x8 a  = *(const bf16x8*)&h2b[l15*YPAD + ko];
            bf16x8 b0 = *(const bf16x8*)&w11t[(size_t)(n0 + l15)*CAT_ + ko];
            bf16x8 b1 = *(const bf16x8*)&w11t[(size_t)(n0 + 16 + l15)*CAT_ + ko];
            d0 = __builtin_amdgcn_mfma_f32_16x16x32_bf16(a,b0,d0,0,0,0);
            d1 = __builtin_amdgcn_mfma_f32_16x16x32_bf16(a,b1,d1,0,0,0);
        }
        for (int r=0;r<4;r++) {
            gv11f[(size_t)(r0 + q*4 + r)*H_ + n0 + l15]      = d0[r];
            gv11f[(size_t)(r0 + q*4 + r)*H_ + n0 + 16 + l15] = d1[r];
        }
    }
}

// ================= edge kernel: MFMA =================
__global__ void __launch_bounds__(256, 3)
edge_mfma(const u16* __restrict__ wsVn, const void* __restrict__ hE, const int* __restrict__ idxn,
          const u16* __restrict__ w11t,
          const u16* __restrict__ w12t, const void* __restrict__ b12,
          const u16* __restrict__ w13t, const void* __restrict__ b13,
          const void* __restrict__ g3, const void* __restrict__ be3,
          const float* __restrict__ gv11f,
          const int* __restrict__ flags,
          float* __restrict__ outE)
{
    __shared__ __align__(16) u16 Xs[K_*XAP];    // X tile; aliased as Y2, then fp32 M
    __shared__ __align__(16) u16 Y1s[K_*YPAD];
    __shared__ int idxs[K_];

    const int bn  = blockIdx.x;
    const int b   = bn >> 10;
    const int tid = threadIdx.x;
    const int lane = tid & 63, w = tid >> 6;

    const int fHE = flags[1];
    const int fb12 = flags[14], fb13 = flags[16];
    const int fg3 = flags[25], fbe3 = flags[26];

    if (tid < K_) idxs[tid] = idxn[bn*K_ + tid];
    __syncthreads();

    const u16* hVb = wsVn + (size_t)b*N_*H_;
    for (int u = tid; u < 768; u += 256) {
        const int row = u >> 4, c8 = (u & 15) << 3;
        cp8(&Xs[row*XAP + c8], hE, ((size_t)bn*K_ + row)*H_ + c8, fHE);
        *(uint4*)&Xs[row*XAP + H_ + c8] = *(const uint4*)&hVb[(size_t)idxs[row]*H_ + c8];
    }
    __syncthreads();

    const int l15 = lane & 15, q = lane >> 4, n0 = w*32;

    // GEMM1: C-init from gv11 (center + b11, from ffn_fused)
#pragma unroll 1
    for (int ct = 0; ct < 2; ct++) {
        f32x4 acc[3];
        const float g = gv11f[(size_t)bn*H_ + n0 + ct*16 + l15];
        for (int mt=0; mt<3; mt++) for (int r=0; r<4; r++) acc[mt][r] = g;
        mfma3x1<256, XAP, CAT_, H_>(Xs, w11t, tid, ct, acc);
        epi_gelu1<false>(acc, nullptr, 0, Y1s, tid, ct);
    }
    __syncthreads();

    u16* Y2s = Xs;
#pragma unroll 1
    for (int ct = 0; ct < 2; ct++) {
        f32x4 acc[3] = {fzero(), fzero(), fzero()};
        mfma3x1<H_, YPAD, H_, 0>(Y1s, w12t, tid, ct, acc);
        epi_gelu1<true>(acc, b12, fb12, Y2s, tid, ct);
    }
    __syncthreads();

    // GEMM3: NAMED static accumulators (rule #20; R4 post-mortem).
    f32x4 accA[3] = {fzero(), fzero(), fzero()};
    f32x4 accB[3] = {fzero(), fzero(), fzero()};
    mfma3x1<H_, YPAD, H_, 0>(Y2s, w13t, tid, 0, accA);
    mfma3x1<H_, YPAD, H_, 0>(Y2s, w13t, tid, 1, accB);
    __syncthreads();                  // all layer-3 reads of Y2 (Xs) done
    float* Ms = (float*)Xs;           // fp32 M tile [48][MPAD]
    {
        const int colA = n0 + l15;
        const float bvA = ldf(b13, colA, fb13);
        for (int mt=0; mt<3; mt++)
            for (int r=0; r<4; r++)
                Ms[(mt*16 + q*4 + r)*MPAD + colA] = accA[mt][r] + bvA;
        const int colB = n0 + 16 + l15;
        const float bvB = ldf(b13, colB, fb13);
        for (int mt=0; mt<3; mt++)
            for (int r=0; r<4; r++)
                Ms[(mt*16 + q*4 + r)*MPAD + colB] = accB[mt][r] + bvB;
    }
    __syncthreads();

    // h_En = LN(h_E + M), one wave per row, fp32 store
    for (int row = w; row < K_; row += 4) {
        const size_t e0 = ((size_t)bn*K_ + row)*H_;
        float v0 = ldf(hE, e0 + lane,      fHE) + Ms[row*MPAD + lane];
        float v1 = ldf(hE, e0 + lane + 64, fHE) + Ms[row*MPAD + lane + 64];
        float s = v0+v1, ss = v0*v0+v1*v1;
        for (int off=32; off>0; off>>=1) { s += __shfl_xor(s,off); ss += __shfl_xor(ss,off); }
        const float m = s*(1.f/H_);
        const float rstd = rsqrtf(ss*(1.f/H_) - m*m + EPS_);
        outE[e0 + lane]      = (v0-m)*rstd*ldf(g3,lane,fg3)    + ldf(be3,lane,fbe3);
        outE[e0 + lane + 64] = (v1-m)*rstd*ldf(g3,lane+64,fg3) + ldf(be3,lane+64,fbe3);
    }
}

extern "C" void kernel_launch(void* const* d_in, const int* in_sizes, int n_in,
                              void* d_out, int out_size, void* d_ws, size_t ws_size,
                              hipStream_t stream)
{
    const void* hV      = d_in[0];
    const void* hE      = d_in[1];
    const int*  Eidx    = (const int*)d_in[2];
    const void* maskV   = d_in[3];
    const void* maskAtt = d_in[4];
    const void* W1w  = d_in[5];  const void* W1b  = d_in[6];
    const void* W2w  = d_in[7];  const void* W2b  = d_in[8];
    const void* W3w  = d_in[9];  const void* W3b  = d_in[10];
    const void* W11w = d_in[11]; const void* W11b = d_in[12];
    const void* W12w = d_in[13]; const void* W12b = d_in[14];
    const void* W13w = d_in[15]; const void* W13b = d_in[16];
    const void* Winw = d_in[17]; const void* Winb = d_in[18];
    const void* Woutw= d_in[19]; const void* Woutb= d_in[20];
    const void* ln1g = d_in[21]; const void* ln1b = d_in[22];
    const void* ln2g = d_in[23]; const void* ln2b = d_in[24];
    const void* ln3g = d_in[25]; const void* ln3b = d_in[26];

    // ws layout
    u16* ws    = (u16*)d_ws;
    u16* w1t   = ws;                        // 128*384
    u16* w2t   = w1t   + 128*384;           // 128*128
    u16* w3t   = w2t   + 128*128;
    u16* w11t  = w3t   + 128*128;           // 128*384
    u16* w12t  = w11t  + 128*384;
    u16* w13t  = w12t  + 128*128;
    u16* wintt = w13t  + 128*128;           // 512*128
    u16* woutt = wintt + 512*128;           // 128*512
    int* idxn  = (int*)(woutt + 128*512);   // 98304 int32
    u16* wsVn  = (u16*)(idxn + B_*N_*K_);   // 262144 bf16
    float* gv1f  = (float*)(wsVn + B_*N_*H_);   // 262144 f32
    float* hvn1f = gv1f  + (size_t)B_*N_*H_;    // 262144 f32
    float* gv11f = hvn1f + (size_t)B_*N_*H_;    // 262144 f32
    int* flags = (int*)(gv11f + (size_t)B_*N_*H_);  // 27 ints

    Ptrs27 P;
    for (int i = 0; i < 27; i++) { P.p[i] = d_in[i]; P.n[i] = in_sizes[i]; }
    hipLaunchKernelGGL(probe_dtypes, dim3(27), dim3(64), 0, stream, P, flags);

    auto T = [&](const void* src, u16* dst, int ri, int co, int fidx) {
        hipLaunchKernelGGL(repack_t, dim3((ri*co+255)/256), dim3(256), 0, stream, src, dst, ri, co, flags, fidx);
    };
    T(W1w,  w1t,  384, 128, 5);
    T(W2w,  w2t,  128, 128, 7);
    T(W3w,  w3t,  128, 128, 9);
    T(W11w, w11t, 384, 128, 11);
    T(W12w, w12t, 128, 128, 13);
    T(W13w, w13t, 128, 128, 15);
    T(Winw, wintt, 128, 512, 17);
    T(Woutw,woutt, 512, 128, 19);
    hipLaunchKernelGGL(prep_idx, dim3((B_*N_*K_+255)/256), dim3(256), 0, stream, Eidx, idxn, B_*N_*K_, flags);

    float* outV = (float*)d_out;
    float* outE = outV + (size_t)B_*N_*H_;

    hipLaunchKernelGGL(pre_gv1, dim3(B_*N_/16), dim3(256), 0, stream,
                       hV, w1t, W1b, flags, gv1f);
    hipLaunchKernelGGL(node_mfma, dim3(B_*N_), dim3(256), 0, stream,
                       hV, hE, idxn, maskAtt,
                       w1t, w2t, W2b, w3t, W3b,
                       ln1g, ln1b, gv1f, flags, hvn1f);
    hipLaunchKernelGGL(ffn_fused, dim3(B_*N_/16), dim3(256), 0, stream,
                       hvn1f, maskV, wintt, Winb, woutt, Woutb,
                       w11t, W11b, ln2g, ln2b, flags, outV, wsVn, gv11f);
    hipLaunchKernelGGL(edge_mfma, dim3(B_*N_), dim3(256), 0, stream,
                       wsVn, hE, idxn,
                       w11t, w12t, W12b, w13t, W13b,
                       ln3g, ln3b, gv11f, flags, outE);
}

// Round 7
// 304.008 us; speedup vs baseline: 1.4467x; 1.0722x over previous
//
#include <hip/hip_runtime.h>
#include <cstdint>
#include <cstddef>

typedef unsigned short u16;
typedef unsigned int   u32;
typedef __bf16  bf16x8 __attribute__((ext_vector_type(8)));
typedef float   f32x4  __attribute__((ext_vector_type(4)));

#define B_    2
#define N_    1024
#define K_    48
#define H_    128
#define CAT_  384
#define FF_   512
#define XAP   264   // bf16 row pitch for reduced X tile (256+8)
#define YPAD  136   // bf16 row pitch for 128-col tiles (128+8)
#define HIDP  520   // bf16 row pitch for ffn hid tile (512+8)
#define MPAD  132   // fp32 row pitch for 128-col fp32 tiles
#define EPS_  1e-5f
#define INV_SCALE (1.0f/48.0f)

__device__ __forceinline__ float bf2f(u16 u){ u32 x=((u32)u)<<16; float f; __builtin_memcpy(&f,&x,4); return f; }
__device__ __forceinline__ u16 f2bf(float f){ u32 x; __builtin_memcpy(&x,&f,4); x=(x+0x7FFFu+((x>>16)&1u))>>16; return (u16)x; }
__device__ __forceinline__ u32 pk2(float lo, float hi){ return (u32)f2bf(lo) | ((u32)f2bf(hi)<<16); }

// Branch-free exact-GELU: erf via Abramowitz-Stegun 7.1.26 (|err|<=1.5e-7).
__device__ __forceinline__ float gelu_ex(float x){
    const float s = x * 0.7071067811865476f;
    const float a = fabsf(s);
    const float t = __builtin_amdgcn_rcpf(__builtin_fmaf(0.3275911f, a, 1.0f));
    float p = __builtin_fmaf(1.061405429f, t, -1.453152027f);
    p = __builtin_fmaf(p, t,  1.421413741f);
    p = __builtin_fmaf(p, t, -0.284496736f);
    p = __builtin_fmaf(p, t,  0.254829592f);
    p *= t;
    const float e = __expf(-s*s);
    const float erfa = __builtin_fmaf(-p, e, 1.0f);
    const float erf  = __builtin_copysignf(erfa, s);
    return 0.5f*x*(1.0f+erf);
}
__device__ __forceinline__ f32x4 fzero(){ f32x4 v; v[0]=0.f; v[1]=0.f; v[2]=0.f; v[3]=0.f; return v; }

__device__ __forceinline__ float ldf(const void* p, size_t i, int bf){
    return bf ? bf2f(((const u16*)p)[i]) : ((const float*)p)[i];
}
// 8 consecutive elems -> bf16 LDS (dtype-aware)
__device__ __forceinline__ void cp8(u16* dst, const void* src, size_t eoff, int bf){
    if (bf) { *(uint4*)dst = *(const uint4*)((const u16*)src + eoff); }
    else {
        const float4* s = (const float4*)((const float*)src + eoff);
        float4 a = s[0], b = s[1];
        uint4 o; o.x = pk2(a.x,a.y); o.y = pk2(a.z,a.w); o.z = pk2(b.x,b.y); o.w = pk2(b.z,b.w);
        *(uint4*)dst = o;
    }
}

// ---------------- dtype probes ----------------
__device__ int probe_f_d(const void* p, int n_elems){
    const u32 w0 = ((const u32*)p)[0];
    if (w0 == 0x3F803F80u) return 1;
    if (w0 == 0x3F800000u) return 0;
    const u16* s = (const u16*)p;
    int m = n_elems < 128 ? n_elems : 128;
    for (int j = 0; j < m; j++) { float v = fabsf(bf2f(s[j])); if (v > 1e6f) return 0; }
    return 1;
}
__device__ int probe_i_d(const int* p){
    const u32* s = (const u32*)p;
    for (int j = 0; j < 128; j++) if (s[2*j+1] != 0u) return 0;
    return 1;
}
struct Ptrs27 { const void* p[27]; int n[27]; };

// ================= mega_prep: all repacks + idx + probes in ONE launch =================
// R6 post-mortem: sum(kernel dur) ~218 µs vs wall 326 µs — ~108 µs was launch
// gaps across 11 prologue micro-kernels. This kernel replaces probe_dtypes +
// 8x repack_t + prep_idx (10 launches -> 1). Repack/idx blocks probe their own
// source inline (thread 0 + LDS broadcast) so there is NO intra-kernel
// dependency on the flags written by the probe blocks; downstream kernels read
// flags safely because in-stream launches serialize.
__global__ void __launch_bounds__(256)
mega_prep(Ptrs27 P, u16* __restrict__ ws, int* __restrict__ flags)
{
    // ws layout (u16 units) — must match kernel_launch
    u16* w1t   = ws;
    u16* w2t   = w1t   + 128*384;
    u16* w3t   = w2t   + 128*128;
    u16* w11t  = w3t   + 128*128;
    u16* w12t  = w11t  + 128*384;
    u16* w13t  = w12t  + 128*128;
    u16* wintt = w13t  + 128*128;
    u16* woutt = wintt + 512*128;
    int* idxn  = (int*)(woutt + 128*512);

    __shared__ int sbf;
    const int blk = blockIdx.x;
    const int tid = threadIdx.x;

    if (blk >= 1536) {                 // ---- probe job: 27 blocks ----
        const int t = blk - 1536;
        if (tid == 0)
            flags[t] = (t == 2) ? probe_i_d((const int*)P.p[t]) : probe_f_d(P.p[t], P.n[t]);
        return;
    }
    if (blk >= 1152) {                 // ---- prep_idx: 384 blocks ----
        const int* s = (const int*)P.p[2];
        if (tid == 0) sbf = probe_i_d(s);
        __syncthreads();
        const int w64 = sbf;
        const int i = (blk - 1152)*256 + tid;
        if (i < B_*N_*K_) idxn[i] = w64 ? s[2*i] : s[i];
        return;
    }
    // ---- weight repack jobs: [ri][co] -> bf16 [co][ri] ----
    const void* src; u16* dst; int ri, co, rel;
    if      (blk <  192) { src=P.p[5];  dst=w1t;   ri=384; co=128; rel=blk;      }
    else if (blk <  256) { src=P.p[7];  dst=w2t;   ri=128; co=128; rel=blk-192;  }
    else if (blk <  320) { src=P.p[9];  dst=w3t;   ri=128; co=128; rel=blk-256;  }
    else if (blk <  512) { src=P.p[11]; dst=w11t;  ri=384; co=128; rel=blk-320;  }
    else if (blk <  576) { src=P.p[13]; dst=w12t;  ri=128; co=128; rel=blk-512;  }
    else if (blk <  640) { src=P.p[15]; dst=w13t;  ri=128; co=128; rel=blk-576;  }
    else if (blk <  896) { src=P.p[17]; dst=wintt; ri=128; co=512; rel=blk-640;  }
    else                 { src=P.p[19]; dst=woutt; ri=512; co=128; rel=blk-896;  }
    if (tid == 0) sbf = probe_f_d(src, 128);
    __syncthreads();
    const int bf = sbf;
    const int i = rel*256 + tid;
    if (i < ri*co) {
        const int o = i % co, r = i / co;
        dst[(size_t)o*ri + r] = bf ? ((const u16*)src)[i] : f2bf(((const float*)src)[i]);
    }
}

// ---- single-column-block GEMM pass (register-pressure-reduced) ----
// 48xKD (LDS, u16 pitch AP) @ W^T rows (pitch LD, col-offset KOFF), ONE 16-col
// block ct of this wave's 32-col range -> acc[3]. acc must be statically indexed
// at call sites (rule #20; R4 post-mortem).
template<int KD, int AP, int LD, int KOFF>
__device__ __forceinline__ void mfma3x1(const u16* As, const u16* __restrict__ wt, int tid, int ct, f32x4 acc[3])
{
    const int lane = tid & 63;
    const int l15  = lane & 15, q = lane >> 4;
    const int n0   = (tid >> 6) * 32 + ct*16;
    for (int k0 = 0; k0 < KD; k0 += 32) {
        const int ko = k0 + q*8;
        bf16x8 b0 = *(const bf16x8*)&wt[(size_t)(n0 + l15)*LD + KOFF + ko];
        bf16x8 a0 = *(const bf16x8*)&As[(l15     )*AP + ko];
        bf16x8 a1 = *(const bf16x8*)&As[(l15 + 16)*AP + ko];
        bf16x8 a2 = *(const bf16x8*)&As[(l15 + 32)*AP + ko];
        acc[0] = __builtin_amdgcn_mfma_f32_16x16x32_bf16(a0,b0,acc[0],0,0,0);
        acc[1] = __builtin_amdgcn_mfma_f32_16x16x32_bf16(a1,b0,acc[1],0,0,0);
        acc[2] = __builtin_amdgcn_mfma_f32_16x16x32_bf16(a2,b0,acc[2],0,0,0);
    }
}
// D[row=mt*16+(lane>>4)*4+r][col=(wave*32)+ct*16+(lane&15)]  (m89-verified C/D mapping)
template<bool BIAS>
__device__ __forceinline__ void epi_gelu1(const f32x4 acc[3], const void* __restrict__ bias, int bf,
                                          u16* Outs, int tid, int ct)
{
    const int lane = tid & 63, l15 = lane & 15, q = lane >> 4;
    const int col = (tid>>6)*32 + ct*16 + l15;
    float bv = 0.f;
    if constexpr (BIAS) bv = ldf(bias, col, bf);
    for (int mt = 0; mt < 3; mt++)
        for (int r = 0; r < 4; r++)
            Outs[(mt*16 + q*4 + r)*YPAD + col] = f2bf(gelu_ex(acc[mt][r] + bv));
}

// ================= pre_gv1: gv1 = bf16(hV) @ W1[0:128,:] + b1, all 2048 rows =================
__global__ void __launch_bounds__(256, 2)
pre_gv1(const void* __restrict__ hV, const u16* __restrict__ w1t, const void* __restrict__ b1,
        const int* __restrict__ flags, float* __restrict__ gv1f)
{
    __shared__ __align__(16) u16 Ah[16*YPAD];
    const int r0 = blockIdx.x*16;
    const int tid = threadIdx.x, lane = tid & 63, w = tid >> 6;
    const int l15 = lane & 15, q = lane >> 4;
    const int fHV = flags[0], fb1 = flags[6];

    { const int row = tid >> 4, c8 = (tid & 15) << 3;
      cp8(&Ah[row*YPAD + c8], hV, (size_t)(r0+row)*H_ + c8, fHV); }
    __syncthreads();

    const int n0 = w*32;
    f32x4 a0, a1;
    { float b0v = ldf(b1, n0+l15, fb1), b1v = ldf(b1, n0+16+l15, fb1);
      for (int r=0;r<4;r++){ a0[r]=b0v; a1[r]=b1v; } }
#pragma unroll 1
    for (int k0 = 0; k0 < H_; k0 += 32) {
        const int ko = k0 + q*8;
        bf16x8 a  = *(const bf16x8*)&Ah[l15*YPAD + ko];
        bf16x8 b0 = *(const bf16x8*)&w1t[(size_t)(n0 + l15)*CAT_ + ko];
        bf16x8 b1 = *(const bf16x8*)&w1t[(size_t)(n0 + 16 + l15)*CAT_ + ko];
        a0 = __builtin_amdgcn_mfma_f32_16x16x32_bf16(a,b0,a0,0,0,0);
        a1 = __builtin_amdgcn_mfma_f32_16x16x32_bf16(a,b1,a1,0,0,0);
    }
    for (int r=0;r<4;r++) {
        gv1f[(size_t)(r0 + q*4 + r)*H_ + n0 + l15]      = a0[r];
        gv1f[(size_t)(r0 + q*4 + r)*H_ + n0 + 16 + l15] = a1[r];
    }
}

// ================= node kernel: message + LN1 only =================
__global__ void __launch_bounds__(256, 3)
node_mfma(const void* __restrict__ hV, const void* __restrict__ hE, const int* __restrict__ idxn,
          const void* __restrict__ maskAtt,
          const u16* __restrict__ w1t,
          const u16* __restrict__ w2t, const void* __restrict__ b2,
          const u16* __restrict__ w3t, const void* __restrict__ b3,
          const void* __restrict__ g1, const void* __restrict__ be1,
          const float* __restrict__ gv1f,
          const int* __restrict__ flags,
          float* __restrict__ hvn1f)
{
    __shared__ __align__(16) u16 Xs[K_*XAP];     // X tile; later aliased as Y2
    __shared__ __align__(16) u16 Y1s[K_*YPAD];
    __shared__ float dhs[H_];
    __shared__ float matt[K_];
    __shared__ int   idxs[K_];
    __shared__ float stats[3];                   // mean, rstd, summask

    const int bn  = blockIdx.x;
    const int b   = bn >> 10;
    const int tid = threadIdx.x;
    const int lane = tid & 63, w = tid >> 6;

    const int fHV = flags[0], fHE = flags[1], fMA = flags[4];
    const int fb2 = flags[8], fb3 = flags[10];
    const int fg1 = flags[21], fbe1 = flags[22];

    if (tid < K_) { idxs[tid] = idxn[bn*K_ + tid]; matt[tid] = ldf(maskAtt, (size_t)bn*K_ + tid, fMA); }
    __syncthreads();
    if (tid == 0) { float s=0.f; for (int k=0;k<K_;k++) s += matt[k]; stats[2] = s; }

    for (int u = tid; u < 768; u += 256) {
        const int row = u >> 4, c8 = (u & 15) << 3;
        cp8(&Xs[row*XAP + c8],      hE, ((size_t)bn*K_ + row)*H_ + c8, fHE);
        cp8(&Xs[row*XAP + H_ + c8], hV, ((size_t)b*N_ + idxs[row])*H_ + c8, fHV);
    }
    __syncthreads();

    const int l15 = lane & 15, q = lane >> 4, n0 = w*32;

    // ---- GEMM1: C-init from gv1 (center term + b1, precomputed) ----
#pragma unroll 1
    for (int ct = 0; ct < 2; ct++) {
        f32x4 acc[3];
        const float g = gv1f[(size_t)bn*H_ + n0 + ct*16 + l15];
        for (int mt=0; mt<3; mt++) for (int r=0; r<4; r++) acc[mt][r] = g;
        mfma3x1<256, XAP, CAT_, H_>(Xs, w1t, tid, ct, acc);   // W1 rows 128..383
        epi_gelu1<false>(acc, nullptr, 0, Y1s, tid, ct);
    }
    __syncthreads();

    u16* Y2s = Xs;
#pragma unroll 1
    for (int ct = 0; ct < 2; ct++) {
        f32x4 acc[3] = {fzero(), fzero(), fzero()};
        mfma3x1<H_, YPAD, H_, 0>(Y1s, w2t, tid, ct, acc);
        epi_gelu1<true>(acc, b2, fb2, Y2s, tid, ct);
    }
    __syncthreads();

#pragma unroll 1
    for (int ct = 0; ct < 2; ct++) {
        f32x4 acc[3] = {fzero(), fzero(), fzero()};
        mfma3x1<H_, YPAD, H_, 0>(Y2s, w3t, tid, ct, acc);
        float s0 = 0.f;
        for (int mt=0; mt<3; mt++)
            for (int r=0; r<4; r++)
                s0 += acc[mt][r]*matt[mt*16 + q*4 + r];
        s0 += __shfl_xor(s0,16); s0 += __shfl_xor(s0,32);
        if (q == 0) {
            const int col = n0 + ct*16 + l15;
            dhs[col] = (s0 + ldf(b3, col, fb3)*stats[2]) * INV_SCALE;
        }
    }
    __syncthreads();

    // ---- LN1 -> hvn1f (fp32 ws; ffn_fused consumes) ----
    if (w == 0) {
        float a = ldf(hV, (size_t)bn*H_ + lane,      fHV) + dhs[lane];
        float c = ldf(hV, (size_t)bn*H_ + lane + 64, fHV) + dhs[lane+64];
        float s = a + c, ss = a*a + c*c;
        for (int off=32; off>0; off>>=1) { s += __shfl_xor(s,off); ss += __shfl_xor(ss,off); }
        if (lane == 0) { float m = s*(1.f/H_); stats[0]=m; stats[1]=rsqrtf(ss*(1.f/H_)-m*m+EPS_); }
    }
    __syncthreads();
    if (tid < H_) {
        float h = ldf(hV, (size_t)bn*H_ + tid, fHV) + dhs[tid];
        hvn1f[(size_t)bn*H_ + tid] = (h - stats[0])*stats[1]*ldf(g1,tid,fg1) + ldf(be1,tid,fbe1);
    }
}

// ================= ffn_fused: FFN + LN2 + mask + gv11, 16 rows/block =================
__global__ void __launch_bounds__(256, 2)
ffn_fused(const float* __restrict__ hvn1f, const void* __restrict__ maskV,
          const u16* __restrict__ wintt, const void* __restrict__ bin,
          const u16* __restrict__ woutt, const void* __restrict__ bout,
          const u16* __restrict__ w11t, const void* __restrict__ b11,
          const void* __restrict__ g2, const void* __restrict__ be2,
          const int* __restrict__ flags,
          float* __restrict__ outV, u16* __restrict__ wsVn, float* __restrict__ gv11f)
{
    __shared__ __align__(16) float hvf[16*H_];     // fp32 hvn1 (residual)
    __shared__ __align__(16) u16   Xh[16*YPAD];    // bf16 A-tile of hvn1
    __shared__ __align__(16) u16   hid[16*HIDP];   // bf16 hidden 16x512
    __shared__ __align__(16) float h2f[16*MPAD];   // fp32 pre-LN2
    __shared__ __align__(16) u16   h2b[16*YPAD];   // bf16 LN2 out (gv11 A-tile)

    const int r0  = blockIdx.x*16;
    const int tid = threadIdx.x, lane = tid & 63, w = tid >> 6;
    const int l15 = lane & 15, q = lane >> 4;
    const int fMV = flags[3], fbin = flags[18], fbout = flags[20];
    const int fb11 = flags[12], fg2 = flags[23], fbe2 = flags[24];

    {   // stage hvn1 rows (fp32 + bf16)
        const int row = tid >> 4, c8 = (tid & 15) << 3;
        const float4* s = (const float4*)&hvn1f[(size_t)(r0+row)*H_ + c8];
        float4 a = s[0], b = s[1];
        *(float4*)&hvf[row*H_ + c8]     = a;
        *(float4*)&hvf[row*H_ + c8 + 4] = b;
        uint4 o; o.x = pk2(a.x,a.y); o.y = pk2(a.z,a.w); o.z = pk2(b.x,b.y); o.w = pk2(b.z,b.w);
        *(uint4*)&Xh[row*YPAD + c8] = o;
    }
    __syncthreads();

    // ---- GEMM1: hid[16x512]; wave w owns cols w*128..+127 (8 ct blocks) ----
    {
        f32x4 acc[8];
#pragma unroll
        for (int ct = 0; ct < 8; ct++) {
            const float bv = ldf(bin, w*128 + ct*16 + l15, fbin);
            for (int r=0;r<4;r++) acc[ct][r] = bv;
        }
#pragma unroll 1
        for (int k0 = 0; k0 < H_; k0 += 32) {
            const int ko = k0 + q*8;
            bf16x8 a = *(const bf16x8*)&Xh[l15*YPAD + ko];
#pragma unroll
            for (int ct = 0; ct < 8; ct++) {
                bf16x8 b = *(const bf16x8*)&wintt[(size_t)(w*128 + ct*16 + l15)*H_ + ko];
                acc[ct] = __builtin_amdgcn_mfma_f32_16x16x32_bf16(a,b,acc[ct],0,0,0);
            }
        }
#pragma unroll
        for (int ct = 0; ct < 8; ct++) {
            const int col = w*128 + ct*16 + l15;
            for (int r=0;r<4;r++)
                hid[(q*4 + r)*HIDP + col] = f2bf(gelu_ex(acc[ct][r]));
        }
    }
    __syncthreads();

    // ---- GEMM2: out 16x128; wave w owns 32 cols; + bout + fp32 residual ----
    {
        const int n0 = w*32;
        f32x4 c0 = fzero(), c1 = fzero();
#pragma unroll 1
        for (int k0 = 0; k0 < FF_; k0 += 32) {
            const int ko = k0 + q*8;
            bf16x8 a  = *(const bf16x8*)&hid[l15*HIDP + ko];
            bf16x8 b0 = *(const bf16x8*)&woutt[(size_t)(n0 + l15)*FF_ + ko];
            bf16x8 b1 = *(const bf16x8*)&woutt[(size_t)(n0 + 16 + l15)*FF_ + ko];
            c0 = __builtin_amdgcn_mfma_f32_16x16x32_bf16(a,b0,c0,0,0,0);
            c1 = __builtin_amdgcn_mfma_f32_16x16x32_bf16(a,b1,c1,0,0,0);
        }
        const float bo0 = ldf(bout, n0+l15, fbout), bo1 = ldf(bout, n0+16+l15, fbout);
        for (int r=0;r<4;r++) {
            const int row = q*4 + r;
            h2f[row*MPAD + n0+l15]    = c0[r] + bo0 + hvf[row*H_ + n0+l15];
            h2f[row*MPAD + n0+16+l15] = c1[r] + bo1 + hvf[row*H_ + n0+16+l15];
        }
    }
    __syncthreads();

    // ---- LN2 + mask; rows w, w+4, w+8, w+12 per wave ----
    for (int row = w; row < 16; row += 4) {
        float v0 = h2f[row*MPAD + lane], v1 = h2f[row*MPAD + lane + 64];
        float s = v0+v1, ss = v0*v0+v1*v1;
        for (int off=32; off>0; off>>=1) { s += __shfl_xor(s,off); ss += __shfl_xor(ss,off); }
        const float m = s*(1.f/H_);
        const float rstd = rsqrtf(ss*(1.f/H_) - m*m + EPS_);
        const float mk = ldf(maskV, r0+row, fMV);
        const float o0 = ((v0-m)*rstd*ldf(g2,lane,fg2)    + ldf(be2,lane,fbe2))    * mk;
        const float o1 = ((v1-m)*rstd*ldf(g2,lane+64,fg2) + ldf(be2,lane+64,fbe2)) * mk;
        outV[(size_t)(r0+row)*H_ + lane]      = o0;
        outV[(size_t)(r0+row)*H_ + lane + 64] = o1;
        const u16 u0 = f2bf(o0), u1 = f2bf(o1);
        wsVn[(size_t)(r0+row)*H_ + lane]      = u0;
        wsVn[(size_t)(r0+row)*H_ + lane + 64] = u1;
        h2b[row*YPAD + lane]      = u0;
        h2b[row*YPAD + lane + 64] = u1;
    }
    __syncthreads();

    // ---- GEMM3: gv11 = h2b @ W11[0:128,:] + b11 (edge center term) ----
    {
        const int n0 = w*32;
        f32x4 d0, d1;
        { float b0v = ldf(b11, n0+l15, fb11), b1v = ldf(b11, n0+16+l15, fb11);
          for (int r=0;r<4;r++){ d0[r]=b0v; d1[r]=b1v; } }
#pragma unroll 1
        for (int k0 = 0; k0 < H_; k0 += 32) {
            const int ko = k0 + q*8;
            bf16x8 a  = *(const bf16x8*)&h2b[l15*YPAD + ko];
            bf16x8 b0 = *(const bf16x8*)&w11t[(size_t)(n0 + l15)*CAT_ + ko];
            bf16x8 b1 = *(const bf16x8*)&w11t[(size_t)(n0 + 16 + l15)*CAT_ + ko];
            d0 = __builtin_amdgcn_mfma_f32_16x16x32_bf16(a,b0,d0,0,0,0);
            d1 = __builtin_amdgcn_mfma_f32_16x16x32_bf16(a,b1,d1,0,0,0);
        }
        for (int r=0;r<4;r++) {
            gv11f[(size_t)(r0 + q*4 + r)*H_ + n0 + l15]      = d0[r];
            gv11f[(size_t)(r0 + q*4 + r)*H_ + n0 + 16 + l15] = d1[r];
        }
    }
}

// ================= edge kernel: MFMA =================
__global__ void __launch_bounds__(256, 3)
edge_mfma(const u16* __restrict__ wsVn, const void* __restrict__ hE, const int* __restrict__ idxn,
          const u16* __restrict__ w11t,
          const u16* __restrict__ w12t, const void* __restrict__ b12,
          const u16* __restrict__ w13t, const void* __restrict__ b13,
          const void* __restrict__ g3, const void* __restrict__ be3,
          const float* __restrict__ gv11f,
          const int* __restrict__ flags,
          float* __restrict__ outE)
{
    __shared__ __align__(16) u16 Xs[K_*XAP];    // X tile; aliased as Y2, then fp32 M
    __shared__ __align__(16) u16 Y1s[K_*YPAD];
    __shared__ int idxs[K_];

    const int bn  = blockIdx.x;
    const int b   = bn >> 10;
    const int tid = threadIdx.x;
    const int lane = tid & 63, w = tid >> 6;

    const int fHE = flags[1];
    const int fb12 = flags[14], fb13 = flags[16];
    const int fg3 = flags[25], fbe3 = flags[26];

    if (tid < K_) idxs[tid] = idxn[bn*K_ + tid];
    __syncthreads();

    const u16* hVb = wsVn + (size_t)b*N_*H_;
    for (int u = tid; u < 768; u += 256) {
        const int row = u >> 4, c8 = (u & 15) << 3;
        cp8(&Xs[row*XAP + c8], hE, ((size_t)bn*K_ + row)*H_ + c8, fHE);
        *(uint4*)&Xs[row*XAP + H_ + c8] = *(const uint4*)&hVb[(size_t)idxs[row]*H_ + c8];
    }
    __syncthreads();

    const int l15 = lane & 15, q = lane >> 4, n0 = w*32;

    // GEMM1: C-init from gv11 (center + b11, from ffn_fused)
#pragma unroll 1
    for (int ct = 0; ct < 2; ct++) {
        f32x4 acc[3];
        const float g = gv11f[(size_t)bn*H_ + n0 + ct*16 + l15];
        for (int mt=0; mt<3; mt++) for (int r=0; r<4; r++) acc[mt][r] = g;
        mfma3x1<256, XAP, CAT_, H_>(Xs, w11t, tid, ct, acc);
        epi_gelu1<false>(acc, nullptr, 0, Y1s, tid, ct);
    }
    __syncthreads();

    u16* Y2s = Xs;
#pragma unroll 1
    for (int ct = 0; ct < 2; ct++) {
        f32x4 acc[3] = {fzero(), fzero(), fzero()};
        mfma3x1<H_, YPAD, H_, 0>(Y1s, w12t, tid, ct, acc);
        epi_gelu1<true>(acc, b12, fb12, Y2s, tid, ct);
    }
    __syncthreads();

    // GEMM3: NAMED static accumulators (rule #20; R4 post-mortem).
    f32x4 accA[3] = {fzero(), fzero(), fzero()};
    f32x4 accB[3] = {fzero(), fzero(), fzero()};
    mfma3x1<H_, YPAD, H_, 0>(Y2s, w13t, tid, 0, accA);
    mfma3x1<H_, YPAD, H_, 0>(Y2s, w13t, tid, 1, accB);
    __syncthreads();                  // all layer-3 reads of Y2 (Xs) done
    float* Ms = (float*)Xs;           // fp32 M tile [48][MPAD]
    {
        const int colA = n0 + l15;
        const float bvA = ldf(b13, colA, fb13);
        for (int mt=0; mt<3; mt++)
            for (int r=0; r<4; r++)
                Ms[(mt*16 + q*4 + r)*MPAD + colA] = accA[mt][r] + bvA;
        const int colB = n0 + 16 + l15;
        const float bvB = ldf(b13, colB, fb13);
        for (int mt=0; mt<3; mt++)
            for (int r=0; r<4; r++)
                Ms[(mt*16 + q*4 + r)*MPAD + colB] = accB[mt][r] + bvB;
    }
    __syncthreads();

    // h_En = LN(h_E + M), one wave per row, fp32 store
    for (int row = w; row < K_; row += 4) {
        const size_t e0 = ((size_t)bn*K_ + row)*H_;
        float v0 = ldf(hE, e0 + lane,      fHE) + Ms[row*MPAD + lane];
        float v1 = ldf(hE, e0 + lane + 64, fHE) + Ms[row*MPAD + lane + 64];
        float s = v0+v1, ss = v0*v0+v1*v1;
        for (int off=32; off>0; off>>=1) { s += __shfl_xor(s,off); ss += __shfl_xor(ss,off); }
        const float m = s*(1.f/H_);
        const float rstd = rsqrtf(ss*(1.f/H_) - m*m + EPS_);
        outE[e0 + lane]      = (v0-m)*rstd*ldf(g3,lane,fg3)    + ldf(be3,lane,fbe3);
        outE[e0 + lane + 64] = (v1-m)*rstd*ldf(g3,lane+64,fg3) + ldf(be3,lane+64,fbe3);
    }
}

extern "C" void kernel_launch(void* const* d_in, const int* in_sizes, int n_in,
                              void* d_out, int out_size, void* d_ws, size_t ws_size,
                              hipStream_t stream)
{
    const void* hV      = d_in[0];
    const void* hE      = d_in[1];
    const void* maskV   = d_in[3];
    const void* maskAtt = d_in[4];
    const void* W1b  = d_in[6];
    const void* W2b  = d_in[8];
    const void* W3b  = d_in[10];
    const void* W11b = d_in[12];
    const void* W12b = d_in[14];
    const void* W13b = d_in[16];
    const void* Winb = d_in[18];
    const void* Woutb= d_in[20];
    const void* ln1g = d_in[21]; const void* ln1b = d_in[22];
    const void* ln2g = d_in[23]; const void* ln2b = d_in[24];
    const void* ln3g = d_in[25]; const void* ln3b = d_in[26];

    // ws layout (u16 units) — mirrored inside mega_prep
    u16* ws    = (u16*)d_ws;
    u16* w1t   = ws;                        // 128*384
    u16* w2t   = w1t   + 128*384;           // 128*128
    u16* w3t   = w2t   + 128*128;
    u16* w11t  = w3t   + 128*128;           // 128*384
    u16* w12t  = w11t  + 128*384;
    u16* w13t  = w12t  + 128*128;
    u16* wintt = w13t  + 128*128;           // 512*128
    u16* woutt = wintt + 512*128;           // 128*512
    int* idxn  = (int*)(woutt + 128*512);   // 98304 int32
    u16* wsVn  = (u16*)(idxn + B_*N_*K_);   // 262144 bf16
    float* gv1f  = (float*)(wsVn + B_*N_*H_);   // 262144 f32
    float* hvn1f = gv1f  + (size_t)B_*N_*H_;    // 262144 f32
    float* gv11f = hvn1f + (size_t)B_*N_*H_;    // 262144 f32
    int* flags = (int*)(gv11f + (size_t)B_*N_*H_);  // 27 ints

    Ptrs27 P;
    for (int i = 0; i < 27; i++) { P.p[i] = d_in[i]; P.n[i] = in_sizes[i]; }

    // ONE prep launch: 8 repacks (blocks 0..1151) + prep_idx (1152..1535) + probes (1536..1562)
    hipLaunchKernelGGL(mega_prep, dim3(1563), dim3(256), 0, stream, P, ws, flags);

    float* outV = (float*)d_out;
    float* outE = outV + (size_t)B_*N_*H_;

    hipLaunchKernelGGL(pre_gv1, dim3(B_*N_/16), dim3(256), 0, stream,
                       hV, w1t, W1b, flags, gv1f);
    hipLaunchKernelGGL(node_mfma, dim3(B_*N_), dim3(256), 0, stream,
                       hV, hE, idxn, maskAtt,
                       w1t, w2t, W2b, w3t, W3b,
                       ln1g, ln1b, gv1f, flags, hvn1f);
    hipLaunchKernelGGL(ffn_fused, dim3(B_*N_/16), dim3(256), 0, stream,
                       hvn1f, maskV, wintt, Winb, woutt, Woutb,
                       w11t, W11b, ln2g, ln2b, flags, outV, wsVn, gv11f);
    hipLaunchKernelGGL(edge_mfma, dim3(B_*N_), dim3(256), 0, stream,
                       wsVn, hE, idxn,
                       w11t, w12t, W12b, w13t, W13b,
                       ln3g, ln3b, gv11f, flags, outE);
}

// Round 8
// 289.991 us; speedup vs baseline: 1.5166x; 1.0483x over previous
//
#include <hip/hip_runtime.h>
#include <cstdint>
#include <cstddef>

typedef unsigned short u16;
typedef unsigned int   u32;
typedef __bf16  bf16x8 __attribute__((ext_vector_type(8)));
typedef float   f32x4  __attribute__((ext_vector_type(4)));

#define B_    2
#define N_    1024
#define K_    48
#define H_    128
#define CAT_  384
#define FF_   512
#define XAP   264   // bf16 row pitch for reduced X tile (256+8)
#define YPAD  136   // bf16 row pitch for 128-col tiles (128+8)
#define HIDP  520   // bf16 row pitch for ffn hid tile (512+8)
#define MPAD  132   // fp32 row pitch for 128-col fp32 tiles
#define MSP   68    // fp32 row pitch for 64-col M half-tiles (edge)
#define EPS_  1e-5f
#define INV_SCALE (1.0f/48.0f)

__device__ __forceinline__ float bf2f(u16 u){ u32 x=((u32)u)<<16; float f; __builtin_memcpy(&f,&x,4); return f; }
__device__ __forceinline__ u16 f2bf(float f){ u32 x; __builtin_memcpy(&x,&f,4); x=(x+0x7FFFu+((x>>16)&1u))>>16; return (u16)x; }
__device__ __forceinline__ u32 pk2(float lo, float hi){ return (u32)f2bf(lo) | ((u32)f2bf(hi)<<16); }

// Branch-free exact-GELU: erf via Abramowitz-Stegun 7.1.26 (|err|<=1.5e-7).
__device__ __forceinline__ float gelu_ex(float x){
    const float s = x * 0.7071067811865476f;
    const float a = fabsf(s);
    const float t = __builtin_amdgcn_rcpf(__builtin_fmaf(0.3275911f, a, 1.0f));
    float p = __builtin_fmaf(1.061405429f, t, -1.453152027f);
    p = __builtin_fmaf(p, t,  1.421413741f);
    p = __builtin_fmaf(p, t, -0.284496736f);
    p = __builtin_fmaf(p, t,  0.254829592f);
    p *= t;
    const float e = __expf(-s*s);
    const float erfa = __builtin_fmaf(-p, e, 1.0f);
    const float erf  = __builtin_copysignf(erfa, s);
    return 0.5f*x*(1.0f+erf);
}
__device__ __forceinline__ f32x4 fzero(){ f32x4 v; v[0]=0.f; v[1]=0.f; v[2]=0.f; v[3]=0.f; return v; }

__device__ __forceinline__ float ldf(const void* p, size_t i, int bf){
    return bf ? bf2f(((const u16*)p)[i]) : ((const float*)p)[i];
}
// 8 consecutive elems -> bf16 LDS (dtype-aware)
__device__ __forceinline__ void cp8(u16* dst, const void* src, size_t eoff, int bf){
    if (bf) { *(uint4*)dst = *(const uint4*)((const u16*)src + eoff); }
    else {
        const float4* s = (const float4*)((const float*)src + eoff);
        float4 a = s[0], b = s[1];
        uint4 o; o.x = pk2(a.x,a.y); o.y = pk2(a.z,a.w); o.z = pk2(b.x,b.y); o.w = pk2(b.z,b.w);
        *(uint4*)dst = o;
    }
}

// ---------------- dtype probes ----------------
__device__ int probe_f_d(const void* p, int n_elems){
    const u32 w0 = ((const u32*)p)[0];
    if (w0 == 0x3F803F80u) return 1;
    if (w0 == 0x3F800000u) return 0;
    const u16* s = (const u16*)p;
    int m = n_elems < 128 ? n_elems : 128;
    for (int j = 0; j < m; j++) { float v = fabsf(bf2f(s[j])); if (v > 1e6f) return 0; }
    return 1;
}
__device__ int probe_i_d(const int* p){
    const u32* s = (const u32*)p;
    for (int j = 0; j < 128; j++) if (s[2*j+1] != 0u) return 0;
    return 1;
}
struct Ptrs27 { const void* p[27]; int n[27]; };

// ================= mega_prep: all repacks + idx + probes in ONE launch =================
__global__ void __launch_bounds__(256)
mega_prep(Ptrs27 P, u16* __restrict__ ws, int* __restrict__ flags)
{
    // ws layout (u16 units) — must match kernel_launch
    u16* w1t   = ws;
    u16* w2t   = w1t   + 128*384;
    u16* w3t   = w2t   + 128*128;
    u16* w11t  = w3t   + 128*128;
    u16* w12t  = w11t  + 128*384;
    u16* w13t  = w12t  + 128*128;
    u16* wintt = w13t  + 128*128;
    u16* woutt = wintt + 512*128;
    int* idxn  = (int*)(woutt + 128*512);

    __shared__ int sbf;
    const int blk = blockIdx.x;
    const int tid = threadIdx.x;

    if (blk >= 1536) {                 // ---- probe job: 27 blocks ----
        const int t = blk - 1536;
        if (tid == 0)
            flags[t] = (t == 2) ? probe_i_d((const int*)P.p[t]) : probe_f_d(P.p[t], P.n[t]);
        return;
    }
    if (blk >= 1152) {                 // ---- prep_idx: 384 blocks ----
        const int* s = (const int*)P.p[2];
        if (tid == 0) sbf = probe_i_d(s);
        __syncthreads();
        const int w64 = sbf;
        const int i = (blk - 1152)*256 + tid;
        if (i < B_*N_*K_) idxn[i] = w64 ? s[2*i] : s[i];
        return;
    }
    // ---- weight repack jobs: [ri][co] -> bf16 [co][ri] ----
    const void* src; u16* dst; int ri, co, rel;
    if      (blk <  192) { src=P.p[5];  dst=w1t;   ri=384; co=128; rel=blk;      }
    else if (blk <  256) { src=P.p[7];  dst=w2t;   ri=128; co=128; rel=blk-192;  }
    else if (blk <  320) { src=P.p[9];  dst=w3t;   ri=128; co=128; rel=blk-256;  }
    else if (blk <  512) { src=P.p[11]; dst=w11t;  ri=384; co=128; rel=blk-320;  }
    else if (blk <  576) { src=P.p[13]; dst=w12t;  ri=128; co=128; rel=blk-512;  }
    else if (blk <  640) { src=P.p[15]; dst=w13t;  ri=128; co=128; rel=blk-576;  }
    else if (blk <  896) { src=P.p[17]; dst=wintt; ri=128; co=512; rel=blk-640;  }
    else                 { src=P.p[19]; dst=woutt; ri=512; co=128; rel=blk-896;  }
    if (tid == 0) sbf = probe_f_d(src, 128);
    __syncthreads();
    const int bf = sbf;
    const int i = rel*256 + tid;
    if (i < ri*co) {
        const int o = i % co, r = i / co;
        dst[(size_t)o*ri + r] = bf ? ((const u16*)src)[i] : f2bf(((const float*)src)[i]);
    }
}

// ---- single-column-block GEMM pass (register-pressure-reduced) ----
// acc must be statically indexed at call sites (rule #20; R4 post-mortem).
template<int KD, int AP, int LD, int KOFF>
__device__ __forceinline__ void mfma3x1(const u16* As, const u16* __restrict__ wt, int tid, int ct, f32x4 acc[3])
{
    const int lane = tid & 63;
    const int l15  = lane & 15, q = lane >> 4;
    const int n0   = (tid >> 6) * 32 + ct*16;
    for (int k0 = 0; k0 < KD; k0 += 32) {
        const int ko = k0 + q*8;
        bf16x8 b0 = *(const bf16x8*)&wt[(size_t)(n0 + l15)*LD + KOFF + ko];
        bf16x8 a0 = *(const bf16x8*)&As[(l15     )*AP + ko];
        bf16x8 a1 = *(const bf16x8*)&As[(l15 + 16)*AP + ko];
        bf16x8 a2 = *(const bf16x8*)&As[(l15 + 32)*AP + ko];
        acc[0] = __builtin_amdgcn_mfma_f32_16x16x32_bf16(a0,b0,acc[0],0,0,0);
        acc[1] = __builtin_amdgcn_mfma_f32_16x16x32_bf16(a1,b0,acc[1],0,0,0);
        acc[2] = __builtin_amdgcn_mfma_f32_16x16x32_bf16(a2,b0,acc[2],0,0,0);
    }
}
// D[row=mt*16+(lane>>4)*4+r][col=(wave*32)+ct*16+(lane&15)]  (m89-verified C/D mapping)
template<bool BIAS>
__device__ __forceinline__ void epi_gelu1(const f32x4 acc[3], const void* __restrict__ bias, int bf,
                                          u16* Outs, int tid, int ct)
{
    const int lane = tid & 63, l15 = lane & 15, q = lane >> 4;
    const int col = (tid>>6)*32 + ct*16 + l15;
    float bv = 0.f;
    if constexpr (BIAS) bv = ldf(bias, col, bf);
    for (int mt = 0; mt < 3; mt++)
        for (int r = 0; r < 4; r++)
            Outs[(mt*16 + q*4 + r)*YPAD + col] = f2bf(gelu_ex(acc[mt][r] + bv));
}

// ================= pre_gv1: gv1 = bf16(hV) @ W1[0:128,:] + b1, all 2048 rows =================
__global__ void __launch_bounds__(256, 2)
pre_gv1(const void* __restrict__ hV, const u16* __restrict__ w1t, const void* __restrict__ b1,
        const int* __restrict__ flags, float* __restrict__ gv1f)
{
    __shared__ __align__(16) u16 Ah[16*YPAD];
    const int r0 = blockIdx.x*16;
    const int tid = threadIdx.x, lane = tid & 63, w = tid >> 6;
    const int l15 = lane & 15, q = lane >> 4;
    const int fHV = flags[0], fb1 = flags[6];

    { const int row = tid >> 4, c8 = (tid & 15) << 3;
      cp8(&Ah[row*YPAD + c8], hV, (size_t)(r0+row)*H_ + c8, fHV); }
    __syncthreads();

    const int n0 = w*32;
    f32x4 a0, a1;
    { float b0v = ldf(b1, n0+l15, fb1), b1v = ldf(b1, n0+16+l15, fb1);
      for (int r=0;r<4;r++){ a0[r]=b0v; a1[r]=b1v; } }
#pragma unroll 1
    for (int k0 = 0; k0 < H_; k0 += 32) {
        const int ko = k0 + q*8;
        bf16x8 a  = *(const bf16x8*)&Ah[l15*YPAD + ko];
        bf16x8 b0 = *(const bf16x8*)&w1t[(size_t)(n0 + l15)*CAT_ + ko];
        bf16x8 b1 = *(const bf16x8*)&w1t[(size_t)(n0 + 16 + l15)*CAT_ + ko];
        a0 = __builtin_amdgcn_mfma_f32_16x16x32_bf16(a,b0,a0,0,0,0);
        a1 = __builtin_amdgcn_mfma_f32_16x16x32_bf16(a,b1,a1,0,0,0);
    }
    for (int r=0;r<4;r++) {
        gv1f[(size_t)(r0 + q*4 + r)*H_ + n0 + l15]      = a0[r];
        gv1f[(size_t)(r0 + q*4 + r)*H_ + n0 + 16 + l15] = a1[r];
    }
}

// ================= node kernel: message + LN1 only =================
// (256,4): cap 128 total regs -> 4 waves/SIMD. R1 spilled at this cap, but the
// pressure sites (full-unroll GEMVs, fused 2-ct acc, FFN) are gone since R4-R6.
// Spill tripwire: WRITE_SIZE must stay 1,024 KB (hvn1f only).
__global__ void __launch_bounds__(256, 4)
node_mfma(const void* __restrict__ hV, const void* __restrict__ hE, const int* __restrict__ idxn,
          const void* __restrict__ maskAtt,
          const u16* __restrict__ w1t,
          const u16* __restrict__ w2t, const void* __restrict__ b2,
          const u16* __restrict__ w3t, const void* __restrict__ b3,
          const void* __restrict__ g1, const void* __restrict__ be1,
          const float* __restrict__ gv1f,
          const int* __restrict__ flags,
          float* __restrict__ hvn1f)
{
    __shared__ __align__(16) u16 Xs[K_*XAP];     // X tile; later aliased as Y2
    __shared__ __align__(16) u16 Y1s[K_*YPAD];
    __shared__ float dhs[H_];
    __shared__ float matt[K_];
    __shared__ int   idxs[K_];
    __shared__ float stats[3];                   // mean, rstd, summask

    const int bn  = blockIdx.x;
    const int b   = bn >> 10;
    const int tid = threadIdx.x;
    const int lane = tid & 63, w = tid >> 6;

    const int fHV = flags[0], fHE = flags[1], fMA = flags[4];
    const int fb2 = flags[8], fb3 = flags[10];
    const int fg1 = flags[21], fbe1 = flags[22];

    if (tid < K_) { idxs[tid] = idxn[bn*K_ + tid]; matt[tid] = ldf(maskAtt, (size_t)bn*K_ + tid, fMA); }
    __syncthreads();
    if (tid == 0) { float s=0.f; for (int k=0;k<K_;k++) s += matt[k]; stats[2] = s; }

    for (int u = tid; u < 768; u += 256) {
        const int row = u >> 4, c8 = (u & 15) << 3;
        cp8(&Xs[row*XAP + c8],      hE, ((size_t)bn*K_ + row)*H_ + c8, fHE);
        cp8(&Xs[row*XAP + H_ + c8], hV, ((size_t)b*N_ + idxs[row])*H_ + c8, fHV);
    }
    __syncthreads();

    const int l15 = lane & 15, q = lane >> 4, n0 = w*32;

    // ---- GEMM1: C-init from gv1 (center term + b1, precomputed) ----
#pragma unroll 1
    for (int ct = 0; ct < 2; ct++) {
        f32x4 acc[3];
        const float g = gv1f[(size_t)bn*H_ + n0 + ct*16 + l15];
        for (int mt=0; mt<3; mt++) for (int r=0; r<4; r++) acc[mt][r] = g;
        mfma3x1<256, XAP, CAT_, H_>(Xs, w1t, tid, ct, acc);   // W1 rows 128..383
        epi_gelu1<false>(acc, nullptr, 0, Y1s, tid, ct);
    }
    __syncthreads();

    u16* Y2s = Xs;
#pragma unroll 1
    for (int ct = 0; ct < 2; ct++) {
        f32x4 acc[3] = {fzero(), fzero(), fzero()};
        mfma3x1<H_, YPAD, H_, 0>(Y1s, w2t, tid, ct, acc);
        epi_gelu1<true>(acc, b2, fb2, Y2s, tid, ct);
    }
    __syncthreads();

#pragma unroll 1
    for (int ct = 0; ct < 2; ct++) {
        f32x4 acc[3] = {fzero(), fzero(), fzero()};
        mfma3x1<H_, YPAD, H_, 0>(Y2s, w3t, tid, ct, acc);
        float s0 = 0.f;
        for (int mt=0; mt<3; mt++)
            for (int r=0; r<4; r++)
                s0 += acc[mt][r]*matt[mt*16 + q*4 + r];
        s0 += __shfl_xor(s0,16); s0 += __shfl_xor(s0,32);
        if (q == 0) {
            const int col = n0 + ct*16 + l15;
            dhs[col] = (s0 + ldf(b3, col, fb3)*stats[2]) * INV_SCALE;
        }
    }
    __syncthreads();

    // ---- LN1 -> hvn1f (fp32 ws; ffn_fused consumes) ----
    if (w == 0) {
        float a = ldf(hV, (size_t)bn*H_ + lane,      fHV) + dhs[lane];
        float c = ldf(hV, (size_t)bn*H_ + lane + 64, fHV) + dhs[lane+64];
        float s = a + c, ss = a*a + c*c;
        for (int off=32; off>0; off>>=1) { s += __shfl_xor(s,off); ss += __shfl_xor(ss,off); }
        if (lane == 0) { float m = s*(1.f/H_); stats[0]=m; stats[1]=rsqrtf(ss*(1.f/H_)-m*m+EPS_); }
    }
    __syncthreads();
    if (tid < H_) {
        float h = ldf(hV, (size_t)bn*H_ + tid, fHV) + dhs[tid];
        hvn1f[(size_t)bn*H_ + tid] = (h - stats[0])*stats[1]*ldf(g1,tid,fg1) + ldf(be1,tid,fbe1);
    }
}

// ================= ffn_fused: FFN + LN2 + mask + gv11, 16 rows/block =================
__global__ void __launch_bounds__(256, 2)
ffn_fused(const float* __restrict__ hvn1f, const void* __restrict__ maskV,
          const u16* __restrict__ wintt, const void* __restrict__ bin,
          const u16* __restrict__ woutt, const void* __restrict__ bout,
          const u16* __restrict__ w11t, const void* __restrict__ b11,
          const void* __restrict__ g2, const void* __restrict__ be2,
          const int* __restrict__ flags,
          float* __restrict__ outV, u16* __restrict__ wsVn, float* __restrict__ gv11f)
{
    __shared__ __align__(16) float hvf[16*H_];     // fp32 hvn1 (residual)
    __shared__ __align__(16) u16   Xh[16*YPAD];    // bf16 A-tile of hvn1
    __shared__ __align__(16) u16   hid[16*HIDP];   // bf16 hidden 16x512
    __shared__ __align__(16) float h2f[16*MPAD];   // fp32 pre-LN2
    __shared__ __align__(16) u16   h2b[16*YPAD];   // bf16 LN2 out (gv11 A-tile)

    const int r0  = blockIdx.x*16;
    const int tid = threadIdx.x, lane = tid & 63, w = tid >> 6;
    const int l15 = lane & 15, q = lane >> 4;
    const int fMV = flags[3], fbin = flags[18], fbout = flags[20];
    const int fb11 = flags[12], fg2 = flags[23], fbe2 = flags[24];

    {   // stage hvn1 rows (fp32 + bf16)
        const int row = tid >> 4, c8 = (tid & 15) << 3;
        const float4* s = (const float4*)&hvn1f[(size_t)(r0+row)*H_ + c8];
        float4 a = s[0], b = s[1];
        *(float4*)&hvf[row*H_ + c8]     = a;
        *(float4*)&hvf[row*H_ + c8 + 4] = b;
        uint4 o; o.x = pk2(a.x,a.y); o.y = pk2(a.z,a.w); o.z = pk2(b.x,b.y); o.w = pk2(b.z,b.w);
        *(uint4*)&Xh[row*YPAD + c8] = o;
    }
    __syncthreads();

    // ---- GEMM1: hid[16x512]; wave w owns cols w*128..+127 (8 ct blocks) ----
    {
        f32x4 acc[8];
#pragma unroll
        for (int ct = 0; ct < 8; ct++) {
            const float bv = ldf(bin, w*128 + ct*16 + l15, fbin);
            for (int r=0;r<4;r++) acc[ct][r] = bv;
        }
#pragma unroll 1
        for (int k0 = 0; k0 < H_; k0 += 32) {
            const int ko = k0 + q*8;
            bf16x8 a = *(const bf16x8*)&Xh[l15*YPAD + ko];
#pragma unroll
            for (int ct = 0; ct < 8; ct++) {
                bf16x8 b = *(const bf16x8*)&wintt[(size_t)(w*128 + ct*16 + l15)*H_ + ko];
                acc[ct] = __builtin_amdgcn_mfma_f32_16x16x32_bf16(a,b,acc[ct],0,0,0);
            }
        }
#pragma unroll
        for (int ct = 0; ct < 8; ct++) {
            const int col = w*128 + ct*16 + l15;
            for (int r=0;r<4;r++)
                hid[(q*4 + r)*HIDP + col] = f2bf(gelu_ex(acc[ct][r]));
        }
    }
    __syncthreads();

    // ---- GEMM2: out 16x128; wave w owns 32 cols; + bout + fp32 residual ----
    {
        const int n0 = w*32;
        f32x4 c0 = fzero(), c1 = fzero();
#pragma unroll 1
        for (int k0 = 0; k0 < FF_; k0 += 32) {
            const int ko = k0 + q*8;
            bf16x8 a  = *(const bf16x8*)&hid[l15*HIDP + ko];
            bf16x8 b0 = *(const bf16x8*)&woutt[(size_t)(n0 + l15)*FF_ + ko];
            bf16x8 b1 = *(const bf16x8*)&woutt[(size_t)(n0 + 16 + l15)*FF_ + ko];
            c0 = __builtin_amdgcn_mfma_f32_16x16x32_bf16(a,b0,c0,0,0,0);
            c1 = __builtin_amdgcn_mfma_f32_16x16x32_bf16(a,b1,c1,0,0,0);
        }
        const float bo0 = ldf(bout, n0+l15, fbout), bo1 = ldf(bout, n0+16+l15, fbout);
        for (int r=0;r<4;r++) {
            const int row = q*4 + r;
            h2f[row*MPAD + n0+l15]    = c0[r] + bo0 + hvf[row*H_ + n0+l15];
            h2f[row*MPAD + n0+16+l15] = c1[r] + bo1 + hvf[row*H_ + n0+16+l15];
        }
    }
    __syncthreads();

    // ---- LN2 + mask; rows w, w+4, w+8, w+12 per wave ----
    for (int row = w; row < 16; row += 4) {
        float v0 = h2f[row*MPAD + lane], v1 = h2f[row*MPAD + lane + 64];
        float s = v0+v1, ss = v0*v0+v1*v1;
        for (int off=32; off>0; off>>=1) { s += __shfl_xor(s,off); ss += __shfl_xor(ss,off); }
        const float m = s*(1.f/H_);
        const float rstd = rsqrtf(ss*(1.f/H_) - m*m + EPS_);
        const float mk = ldf(maskV, r0+row, fMV);
        const float o0 = ((v0-m)*rstd*ldf(g2,lane,fg2)    + ldf(be2,lane,fbe2))    * mk;
        const float o1 = ((v1-m)*rstd*ldf(g2,lane+64,fg2) + ldf(be2,lane+64,fbe2)) * mk;
        outV[(size_t)(r0+row)*H_ + lane]      = o0;
        outV[(size_t)(r0+row)*H_ + lane + 64] = o1;
        const u16 u0 = f2bf(o0), u1 = f2bf(o1);
        wsVn[(size_t)(r0+row)*H_ + lane]      = u0;
        wsVn[(size_t)(r0+row)*H_ + lane + 64] = u1;
        h2b[row*YPAD + lane]      = u0;
        h2b[row*YPAD + lane + 64] = u1;
    }
    __syncthreads();

    // ---- GEMM3: gv11 = h2b @ W11[0:128,:] + b11 (edge center term) ----
    {
        const int n0 = w*32;
        f32x4 d0, d1;
        { float b0v = ldf(b11, n0+l15, fb11), b1v = ldf(b11, n0+16+l15, fb11);
          for (int r=0;r<4;r++){ d0[r]=b0v; d1[r]=b1v; } }
#pragma unroll 1
        for (int k0 = 0; k0 < H_; k0 += 32) {
            const int ko = k0 + q*8;
            bf16x8 a  = *(const bf16x8*)&h2b[l15*YPAD + ko];
            bf16x8 b0 = *(const bf16x8*)&w11t[(size_t)(n0 + l15)*CAT_ + ko];
            bf16x8 b1 = *(const bf16x8*)&w11t[(size_t)(n0 + 16 + l15)*CAT_ + ko];
            d0 = __builtin_amdgcn_mfma_f32_16x16x32_bf16(a,b0,d0,0,0,0);
            d1 = __builtin_amdgcn_mfma_f32_16x16x32_bf16(a,b1,d1,0,0,0);
        }
        for (int r=0;r<4;r++) {
            gv11f[(size_t)(r0 + q*4 + r)*H_ + n0 + l15]      = d0[r];
            gv11f[(size_t)(r0 + q*4 + r)*H_ + n0 + 16 + l15] = d1[r];
        }
    }
}

// ================= edge kernel: MFMA =================
// (256,4). GEMM3 restructured into two sequential ct passes with M stored as two
// 48x64 fp32 half-tiles (Ms0 in dead Y1s right after ct=0; Ms1 in Xs after the
// ct=1 pass + barrier) so accA dies before accB lives: peak acc 24 -> 12 regs.
// Half-tile col map: global col c -> tile (c>>4)&1, in-tile col (c>>5)*16+(c&15).
// Wave w, ct writes in-tile col w*16+l15. Cross-tile bank aliasing is 2-way (free).
__global__ void __launch_bounds__(256, 4)
edge_mfma(const u16* __restrict__ wsVn, const void* __restrict__ hE, const int* __restrict__ idxn,
          const u16* __restrict__ w11t,
          const u16* __restrict__ w12t, const void* __restrict__ b12,
          const u16* __restrict__ w13t, const void* __restrict__ b13,
          const void* __restrict__ g3, const void* __restrict__ be3,
          const float* __restrict__ gv11f,
          const int* __restrict__ flags,
          float* __restrict__ outE)
{
    __shared__ __align__(16) u16 Xs[K_*XAP];    // X tile; aliased as Y2, then Ms1
    __shared__ __align__(16) u16 Y1s[K_*YPAD];  // Y1 tile; aliased as Ms0 (48*68*4 = 13,056 B exact)
    __shared__ int idxs[K_];

    const int bn  = blockIdx.x;
    const int b   = bn >> 10;
    const int tid = threadIdx.x;
    const int lane = tid & 63, w = tid >> 6;

    const int fHE = flags[1];
    const int fb12 = flags[14], fb13 = flags[16];
    const int fg3 = flags[25], fbe3 = flags[26];

    if (tid < K_) idxs[tid] = idxn[bn*K_ + tid];
    __syncthreads();

    const u16* hVb = wsVn + (size_t)b*N_*H_;
    for (int u = tid; u < 768; u += 256) {
        const int row = u >> 4, c8 = (u & 15) << 3;
        cp8(&Xs[row*XAP + c8], hE, ((size_t)bn*K_ + row)*H_ + c8, fHE);
        *(uint4*)&Xs[row*XAP + H_ + c8] = *(const uint4*)&hVb[(size_t)idxs[row]*H_ + c8];
    }
    __syncthreads();

    const int l15 = lane & 15, q = lane >> 4, n0 = w*32;

    // GEMM1: C-init from gv11 (center + b11, from ffn_fused)
#pragma unroll 1
    for (int ct = 0; ct < 2; ct++) {
        f32x4 acc[3];
        const float g = gv11f[(size_t)bn*H_ + n0 + ct*16 + l15];
        for (int mt=0; mt<3; mt++) for (int r=0; r<4; r++) acc[mt][r] = g;
        mfma3x1<256, XAP, CAT_, H_>(Xs, w11t, tid, ct, acc);
        epi_gelu1<false>(acc, nullptr, 0, Y1s, tid, ct);
    }
    __syncthreads();

    u16* Y2s = Xs;
#pragma unroll 1
    for (int ct = 0; ct < 2; ct++) {
        f32x4 acc[3] = {fzero(), fzero(), fzero()};
        mfma3x1<H_, YPAD, H_, 0>(Y1s, w12t, tid, ct, acc);
        epi_gelu1<true>(acc, b12, fb12, Y2s, tid, ct);
    }
    __syncthreads();                  // Y2 visible; ALL Y1s reads done -> Y1s reusable

    float* Ms0 = (float*)Y1s;         // fp32 [48][MSP], cols c with (c>>4) even
    {
        f32x4 accA[3] = {fzero(), fzero(), fzero()};
        mfma3x1<H_, YPAD, H_, 0>(Y2s, w13t, tid, 0, accA);
        const float bvA = ldf(b13, n0 + l15, fb13);
        const int ci = w*16 + l15;
        for (int mt=0; mt<3; mt++)
            for (int r=0; r<4; r++)
                Ms0[(mt*16 + q*4 + r)*MSP + ci] = accA[mt][r] + bvA;
    }
    {
        f32x4 accB[3] = {fzero(), fzero(), fzero()};
        mfma3x1<H_, YPAD, H_, 0>(Y2s, w13t, tid, 1, accB);
        __syncthreads();              // all Y2 (Xs) reads done -> Xs reusable
        float* Ms1 = (float*)Xs;      // fp32 [48][MSP], cols c with (c>>4) odd
        const float bvB = ldf(b13, n0 + 16 + l15, fb13);
        const int ci = w*16 + l15;
        for (int mt=0; mt<3; mt++)
            for (int r=0; r<4; r++)
                Ms1[(mt*16 + q*4 + r)*MSP + ci] = accB[mt][r] + bvB;
    }
    __syncthreads();                  // Ms0 + Ms1 visible

    // h_En = LN(h_E + M), one wave per row, fp32 store
    {
        const float* Ms0c = (const float*)Y1s;
        const float* Ms1c = (const float*)Xs;
        const int g0  = lane >> 4;
        const int ci0 = (g0 >> 1)*16 + (lane & 15);   // in-tile col for c=lane
        const int ci1 = ci0 + 32;                     // in-tile col for c=lane+64
        const float* Mt = (g0 & 1) ? Ms1c : Ms0c;
        for (int row = w; row < K_; row += 4) {
            const size_t e0 = ((size_t)bn*K_ + row)*H_;
            float v0 = ldf(hE, e0 + lane,      fHE) + Mt[row*MSP + ci0];
            float v1 = ldf(hE, e0 + lane + 64, fHE) + Mt[row*MSP + ci1];
            float s = v0+v1, ss = v0*v0+v1*v1;
            for (int off=32; off>0; off>>=1) { s += __shfl_xor(s,off); ss += __shfl_xor(ss,off); }
            const float m = s*(1.f/H_);
            const float rstd = rsqrtf(ss*(1.f/H_) - m*m + EPS_);
            outE[e0 + lane]      = (v0-m)*rstd*ldf(g3,lane,fg3)    + ldf(be3,lane,fbe3);
            outE[e0 + lane + 64] = (v1-m)*rstd*ldf(g3,lane+64,fg3) + ldf(be3,lane+64,fbe3);
        }
    }
}

extern "C" void kernel_launch(void* const* d_in, const int* in_sizes, int n_in,
                              void* d_out, int out_size, void* d_ws, size_t ws_size,
                              hipStream_t stream)
{
    const void* hV      = d_in[0];
    const void* hE      = d_in[1];
    const void* maskV   = d_in[3];
    const void* maskAtt = d_in[4];
    const void* W1b  = d_in[6];
    const void* W2b  = d_in[8];
    const void* W3b  = d_in[10];
    const void* W11b = d_in[12];
    const void* W12b = d_in[14];
    const void* W13b = d_in[16];
    const void* Winb = d_in[18];
    const void* Woutb= d_in[20];
    const void* ln1g = d_in[21]; const void* ln1b = d_in[22];
    const void* ln2g = d_in[23]; const void* ln2b = d_in[24];
    const void* ln3g = d_in[25]; const void* ln3b = d_in[26];

    // ws layout (u16 units) — mirrored inside mega_prep
    u16* ws    = (u16*)d_ws;
    u16* w1t   = ws;                        // 128*384
    u16* w2t   = w1t   + 128*384;           // 128*128
    u16* w3t   = w2t   + 128*128;
    u16* w11t  = w3t   + 128*128;           // 128*384
    u16* w12t  = w11t  + 128*384;
    u16* w13t  = w12t  + 128*128;
    u16* wintt = w13t  + 128*128;           // 512*128
    u16* woutt = wintt + 512*128;           // 128*512
    int* idxn  = (int*)(woutt + 128*512);   // 98304 int32
    u16* wsVn  = (u16*)(idxn + B_*N_*K_);   // 262144 bf16
    float* gv1f  = (float*)(wsVn + B_*N_*H_);   // 262144 f32
    float* hvn1f = gv1f  + (size_t)B_*N_*H_;    // 262144 f32
    float* gv11f = hvn1f + (size_t)B_*N_*H_;    // 262144 f32
    int* flags = (int*)(gv11f + (size_t)B_*N_*H_);  // 27 ints

    Ptrs27 P;
    for (int i = 0; i < 27; i++) { P.p[i] = d_in[i]; P.n[i] = in_sizes[i]; }

    // ONE prep launch: 8 repacks (blocks 0..1151) + prep_idx (1152..1535) + probes (1536..1562)
    hipLaunchKernelGGL(mega_prep, dim3(1563), dim3(256), 0, stream, P, ws, flags);

    float* outV = (float*)d_out;
    float* outE = outV + (size_t)B_*N_*H_;

    hipLaunchKernelGGL(pre_gv1, dim3(B_*N_/16), dim3(256), 0, stream,
                       hV, w1t, W1b, flags, gv1f);
    hipLaunchKernelGGL(node_mfma, dim3(B_*N_), dim3(256), 0, stream,
                       hV, hE, idxn, maskAtt,
                       w1t, w2t, W2b, w3t, W3b,
                       ln1g, ln1b, gv1f, flags, hvn1f);
    hipLaunchKernelGGL(ffn_fused, dim3(B_*N_/16), dim3(256), 0, stream,
                       hvn1f, maskV, wintt, Winb, woutt, Woutb,
                       w11t, W11b, ln2g, ln2b, flags, outV, wsVn, gv11f);
    hipLaunchKernelGGL(edge_mfma, dim3(B_*N_), dim3(256), 0, stream,
                       wsVn, hE, idxn,
                       w11t, w12t, W12b, w13t, W13b,
                       ln3g, ln3b, gv11f, flags, outE);
}